// Round 6
// baseline (2513.636 us; speedup 1.0000x reference)
//
#include <hip/hip_runtime.h>
#include <stdint.h>

#define NBOX 1024

typedef unsigned long long u64;
typedef unsigned int u32;
typedef unsigned short u16;

// ---------- bit-exact IoU (matches numpy f32 op-for-op; _rn blocks FMA contraction) ----------
__device__ __forceinline__ float iou_pair(const float4 lb, float larea,
                                          const float4 pb, float parea) {
    float ix1 = fmaxf(lb.x, pb.x);
    float iy1 = fmaxf(lb.y, pb.y);
    float ix2 = fminf(lb.z, pb.z);
    float iy2 = fminf(lb.w, pb.w);
    float w = fmaxf(__fsub_rn(ix2, ix1), 0.0f);
    float h = fmaxf(__fsub_rn(iy2, iy1), 0.0f);
    float inter = __fmul_rn(w, h);
    float denom = __fsub_rn(__fadd_rn(larea, parea), inter);
    return inter / denom;
}

__device__ __forceinline__ u64 umax64(u64 a, u64 b) { return a > b ? a : b; }

// ---------- 32-bit max butterfly via DPP; result valid in lane 63 ----------
__device__ __forceinline__ u32 dpp_max32(u32 v) {
    u32 o;
#define S32(CTRL) \
    o = (u32)__builtin_amdgcn_update_dpp(0, (int)v, CTRL, 0xf, 0xf, true); \
    v = (o > v) ? o : v;
    S32(0x111) S32(0x112) S32(0x114) S32(0x118) S32(0x142) S32(0x143)
#undef S32
    return v;
}

// ---------- 64-bit max butterfly via DPP (rescan path); result valid in lane 63 ----------
__device__ __forceinline__ u64 dpp_max64(u64 v) {
    unsigned lo, hi; u64 o;
#define DPP_STEP(CTRL) \
    lo = (unsigned)__builtin_amdgcn_update_dpp(0, (int)(unsigned)(v & 0xffffffffull), CTRL, 0xf, 0xf, true); \
    hi = (unsigned)__builtin_amdgcn_update_dpp(0, (int)(unsigned)(v >> 32),           CTRL, 0xf, 0xf, true); \
    o = (((u64)hi) << 32) | lo; \
    if (o > v) v = o;
    DPP_STEP(0x111) DPP_STEP(0x112) DPP_STEP(0x114)
    DPP_STEP(0x118) DPP_STEP(0x142) DPP_STEP(0x143)
#undef DPP_STEP
    return v;
}

__device__ __forceinline__ u64 readlane64(u64 v, int l) {
    unsigned lo = (unsigned)__builtin_amdgcn_readlane((int)(unsigned)(v & 0xffffffffull), l);
    unsigned hi = (unsigned)__builtin_amdgcn_readlane((int)(unsigned)(v >> 32), l);
    return (((u64)hi) << 32) | lo;
}

// =====================================================================================
// Kernel A (parallel, 1024 blocks): initial packed key per row
//   key = (ioubits<<21) | (row<<11) | (col<<1) | 1 ;  0 == dead row (max IoU == 0)
// =====================================================================================
__global__ void __launch_bounds__(64) init_rowmax(const float* __restrict__ labels,
                                                  const float* __restrict__ preds,
                                                  u64* __restrict__ key_ws) {
    const int b = blockIdx.x;
    const int lane = threadIdx.x;
    float4 lb = ((const float4*)labels)[b];
    float larea = __fmul_rn(__fsub_rn(lb.z, lb.x), __fsub_rn(lb.w, lb.y));
    float bv = -1.0f; int bc = 0;
    #pragma unroll
    for (int j = 0; j < 16; ++j) {
        int c = lane + (j << 6);
        float4 pb = ((const float4*)preds)[c];
        float parea = __fmul_rn(__fsub_rn(pb.z, pb.x), __fsub_rn(pb.w, pb.y));
        float v = iou_pair(lb, larea, pb, parea);
        if (v > bv || (v == bv && c > bc)) { bv = v; bc = c; }
    }
    u64 pv = ((u64)__float_as_uint(bv) << 10) | (unsigned)bc;
    pv = dpp_max64(pv);
    if (lane == 63) {
        u64 val = pv >> 10;
        key_ws[b] = val ? ((val << 21) | ((u64)b << 11) | ((pv & 1023ull) << 1) | 1ull)
                        : 0ull;
    }
}

// =====================================================================================
// Kernel B: SINGLE-WAVE lazy greedy; split keys (32-bit vals, packed 16-bit cols).
//   storage position == row:  val[row] at lane row&63 reg row>>6; col likewise.
// =====================================================================================

// uniform-j select of this lane's val reg (binary tree, depth 4)
#define SELV(jv, dst) do { \
    u32 _a = ((jv) & 1) ? v1  : v0,  _b = ((jv) & 1) ? v3  : v2;  \
    u32 _c = ((jv) & 1) ? v5  : v4,  _d = ((jv) & 1) ? v7  : v6;  \
    u32 _e = ((jv) & 1) ? v9  : v8,  _f = ((jv) & 1) ? v11 : v10; \
    u32 _g = ((jv) & 1) ? v13 : v12, _h = ((jv) & 1) ? v15 : v14; \
    _a = ((jv) & 2) ? _b : _a; _c = ((jv) & 2) ? _d : _c; \
    _e = ((jv) & 2) ? _f : _e; _g = ((jv) & 2) ? _h : _g; \
    _a = ((jv) & 4) ? _c : _a; _e = ((jv) & 4) ? _g : _e; \
    dst = ((jv) & 8) ? _e : _a; } while (0)

// uniform-k select of this lane's packed col reg (k = j>>1; tree depth 3)
#define SELC(kv, dst) do { \
    u32 _a = ((kv) & 1) ? c1 : c0, _b = ((kv) & 1) ? c3 : c2; \
    u32 _c = ((kv) & 1) ? c5 : c4, _d = ((kv) & 1) ? c7 : c6; \
    _a = ((kv) & 2) ? _b : _a; _c = ((kv) & 2) ? _d : _c; \
    dst = ((kv) & 4) ? _c : _a; } while (0)

// owner lane (row&63) sets val reg (row>>6) to nv
#define ASGV(rowv, nv) do { const int _j = (rowv) >> 6; const bool _o = (lane == ((rowv) & 63)); \
    v0  = (_o && _j == 0)  ? (nv) : v0;  v1  = (_o && _j == 1)  ? (nv) : v1;  \
    v2  = (_o && _j == 2)  ? (nv) : v2;  v3  = (_o && _j == 3)  ? (nv) : v3;  \
    v4  = (_o && _j == 4)  ? (nv) : v4;  v5  = (_o && _j == 5)  ? (nv) : v5;  \
    v6  = (_o && _j == 6)  ? (nv) : v6;  v7  = (_o && _j == 7)  ? (nv) : v7;  \
    v8  = (_o && _j == 8)  ? (nv) : v8;  v9  = (_o && _j == 9)  ? (nv) : v9;  \
    v10 = (_o && _j == 10) ? (nv) : v10; v11 = (_o && _j == 11) ? (nv) : v11; \
    v12 = (_o && _j == 12) ? (nv) : v12; v13 = (_o && _j == 13) ? (nv) : v13; \
    v14 = (_o && _j == 14) ? (nv) : v14; v15 = (_o && _j == 15) ? (nv) : v15; } while (0)

// owner lane sets 16-bit col field for row (reg row>>7, half (row>>6)&1) to nc
#define ASGC(rowv, nc) do { const int _j = (rowv) >> 6; const int _k = _j >> 1; \
    const bool _o = (lane == ((rowv) & 63)); \
    const u32 _m = (_j & 1) ? 0x0000FFFFu : 0xFFFF0000u; \
    const u32 _s = ((u32)(nc)) << ((_j & 1) ? 16 : 0); \
    c0 = (_o && _k == 0) ? ((c0 & _m) | _s) : c0; c1 = (_o && _k == 1) ? ((c1 & _m) | _s) : c1; \
    c2 = (_o && _k == 2) ? ((c2 & _m) | _s) : c2; c3 = (_o && _k == 3) ? ((c3 & _m) | _s) : c3; \
    c4 = (_o && _k == 4) ? ((c4 & _m) | _s) : c4; c5 = (_o && _k == 5) ? ((c5 & _m) | _s) : c5; \
    c6 = (_o && _k == 6) ? ((c6 & _m) | _s) : c6; c7 = (_o && _k == 7) ? ((c7 & _m) | _s) : c7; } while (0)

__global__ void __launch_bounds__(64, 1)
greedy1w(const float* __restrict__ preds,
         const float* __restrict__ labels,
         const u64* __restrict__ key_ws,   // may be null
         float* __restrict__ out) {
    __shared__ float4 pred4s[NBOX];
    __shared__ float4 lab4s[NBOX];
    __shared__ float  parea_s[NBOX];
    __shared__ float  larea_s[NBOX];
    __shared__ u16    perm[NBOX];

    const int lane = (int)threadIdx.x;

    #pragma unroll
    for (int j = 0; j < 16; ++j) {
        int i = lane + (j << 6);
        float4 p = ((const float4*)preds)[i];
        float4 L = ((const float4*)labels)[i];
        pred4s[i] = p;
        lab4s[i]  = L;
        parea_s[i] = __fmul_rn(__fsub_rn(p.z, p.x), __fsub_rn(p.w, p.y));
        larea_s[i] = __fmul_rn(__fsub_rn(L.z, L.x), __fsub_rn(L.w, L.y));
        perm[i] = (u16)i;
    }

    u32 v0, v1, v2, v3, v4, v5, v6, v7, v8, v9, v10, v11, v12, v13, v14, v15;
    u32 c0, c1, c2, c3, c4, c5, c6, c7;
    unsigned myseen = 0;   // bit j: column (lane + 64j) consumed

    // wave-cooperative exact rescan of one (uniform) row over unseen columns.
    // returns (valbits<<10)|col, or 0 if max IoU == 0 (permanently dead).
    auto rescan = [&](int row) -> u64 {
        int pm = (int)perm[row];
        float4 lb = lab4s[pm];
        float la = larea_s[pm];
        u64 best = 0;
        #pragma unroll
        for (int j2 = 0; j2 < 16; ++j2) {
            int cc = lane + (j2 << 6);
            float v = iou_pair(lb, la, pred4s[cc], parea_s[cc]);
            u64 pv = ((u64)__float_as_uint(v) << 10) | (unsigned)cc;
            if ((myseen >> j2) & 1u) pv = 0;
            best = umax64(best, pv);
        }
        best = dpp_max64(best);
        return readlane64(best, 63);   // (val<<10)|col ; val==0 -> dead
    };

    if (key_ws) {
        u64 K; u32 t0, t1;
#define LD2(idx0, CV, VA, VB) \
        K = key_ws[lane + (idx0)];      VA = (u32)(K >> 21); t0 = (u32)((K >> 1) & 1023); \
        K = key_ws[lane + (idx0) + 64]; VB = (u32)(K >> 21); t1 = (u32)((K >> 1) & 1023); \
        CV = t0 | (t1 << 16);
        LD2(0,   c0, v0,  v1)   LD2(128, c1, v2,  v3)
        LD2(256, c2, v4,  v5)   LD2(384, c3, v6,  v7)
        LD2(512, c4, v8,  v9)   LD2(640, c5, v10, v11)
        LD2(768, c6, v12, v13)  LD2(896, c7, v14, v15)
#undef LD2
    } else {
        v0=v1=v2=v3=v4=v5=v6=v7=v8=v9=v10=v11=v12=v13=v14=v15=0;
        c0=c1=c2=c3=c4=c5=c6=c7=0;
        for (int row = 0; row < NBOX; ++row) {
            u64 bm = rescan(row);
            ASGV(row, (u32)(bm >> 10));
            ASGC(row, (u32)(bm & 1023ull));
        }
    }

    // ---- lazy greedy: pick max bound, validate, commit or rescan-and-repick ----
    for (int iter = 0; iter < 8192; ++iter) {
        // per-lane tree over (val<<4)|j : tie -> larger j == larger row
        u64 pm = umax64(umax64(umax64((((u64)v0)  << 4) | 0,  (((u64)v1)  << 4) | 1),
                               umax64((((u64)v2)  << 4) | 2,  (((u64)v3)  << 4) | 3)),
                        umax64(umax64((((u64)v4)  << 4) | 4,  (((u64)v5)  << 4) | 5),
                               umax64((((u64)v6)  << 4) | 6,  (((u64)v7)  << 4) | 7)));
        pm = umax64(pm,
             umax64(umax64(umax64((((u64)v8)  << 4) | 8,  (((u64)v9)  << 4) | 9),
                           umax64((((u64)v10) << 4) | 10, (((u64)v11) << 4) | 11)),
                    umax64(umax64((((u64)v12) << 4) | 12, (((u64)v13) << 4) | 13),
                           umax64((((u64)v14) << 4) | 14, (((u64)v15) << 4) | 15))));
        u32 bv = (u32)(pm >> 4);
        int bj = (int)(pm & 15ull);

        // cross-lane: max val, then largest row among tied lanes (exact tie-break)
        u32 gv = (u32)__builtin_amdgcn_readlane((int)dpp_max32(bv), 63);
        if (!gv) break;                       // all live true-max == 0 -> perm final
        u32 rowc = (bv == gv) ? (u32)((bj << 6) | lane) : 0u;
        const int r = (int)__builtin_amdgcn_readlane((int)dpp_max32(rowc), 63);

        // winner's stored col
        const int jr = r >> 6;
        u32 csel; SELC(jr >> 1, csel);
        u32 cpk = (u32)__builtin_amdgcn_readlane((int)csel, r & 63);
        const int c = (int)((cpk >> ((jr & 1) << 4)) & 0xFFFFu);
        const int jc = c >> 6, lc = c & 63;

        // validate: winner's stored col still unseen?
        u32 sl = (u32)__builtin_amdgcn_readlane((int)myseen, lc);
        if ((sl >> jc) & 1u) {
            u64 bm = rescan(r);               // exact refresh; strictly decreases
            ASGV(r, (u32)(bm >> 10));
            ASGC(r, (u32)(bm & 1023ull));
            continue;                         // re-pick
        }

        // ---- commit: transfer key c -> r, kill c, mark col c seen ----
        u32 vsel; SELV(jc, vsel);
        u32 vc = (u32)__builtin_amdgcn_readlane((int)vsel, lc);     // val of row c
        u32 csel2; SELC(jc >> 1, csel2);
        u32 cpk2 = (u32)__builtin_amdgcn_readlane((int)csel2, lc);
        u32 ccol = (cpk2 >> ((jc & 1) << 4)) & 0xFFFFu;             // col of row c

        int ppr = (int)perm[r], ppc = (int)perm[c];
        if (lane == 0) { perm[r] = (u16)ppc; perm[c] = (u16)ppr; }

        ASGV(r, vc); ASGC(r, ccol);           // r's new content bound (exact-or-stale)
        ASGV(c, 0u);                          // kill c (wins when r == c)
        if (lane == lc) myseen |= 1u << jc;
    }

    // ---- loss = mean |labels[perm] - predictions| ----
    float sum = 0.0f;
    #pragma unroll
    for (int j = 0; j < 16; ++j) {
        int i = lane + (j << 6);
        float4 pb = pred4s[i];
        float4 lb = lab4s[perm[i]];
        sum += fabsf(lb.x - pb.x) + fabsf(lb.y - pb.y) +
               fabsf(lb.z - pb.z) + fabsf(lb.w - pb.w);
    }
    for (int off = 32; off > 0; off >>= 1) sum += __shfl_xor(sum, off, 64);
    if (lane == 0) out[0] = sum * (1.0f / 4096.0f);
}

extern "C" void kernel_launch(void* const* d_in, const int* in_sizes, int n_in,
                              void* d_out, int out_size, void* d_ws, size_t ws_size,
                              hipStream_t stream) {
    const float* preds  = (const float*)d_in[0];   // predictions [1024,4]
    const float* labels = (const float*)d_in[1];   // labels      [1024,4]
    float* out = (float*)d_out;

    const size_t key_bytes = NBOX * sizeof(u64);   // 8 KB
    if (d_ws && ws_size >= key_bytes) {
        u64* key_ws = (u64*)d_ws;
        init_rowmax<<<NBOX, 64, 0, stream>>>(labels, preds, key_ws);
        greedy1w<<<1, 64, 0, stream>>>(preds, labels, key_ws, out);
    } else {
        greedy1w<<<1, 64, 0, stream>>>(preds, labels, nullptr, out);
    }
}

// Round 7
// 2087.317 us; speedup vs baseline: 1.2042x; 1.2042x over previous
//
#include <hip/hip_runtime.h>
#include <stdint.h>

#define NBOX 1024

typedef unsigned long long u64;
typedef unsigned int u32;
typedef unsigned short u16;

// ---------- bit-exact IoU (matches numpy f32 op-for-op; _rn blocks FMA contraction) ----------
__device__ __forceinline__ float iou_pair(const float4 lb, float larea,
                                          const float4 pb, float parea) {
    float ix1 = fmaxf(lb.x, pb.x);
    float iy1 = fmaxf(lb.y, pb.y);
    float ix2 = fminf(lb.z, pb.z);
    float iy2 = fminf(lb.w, pb.w);
    float w = fmaxf(__fsub_rn(ix2, ix1), 0.0f);
    float h = fmaxf(__fsub_rn(iy2, iy1), 0.0f);
    float inter = __fmul_rn(w, h);
    float denom = __fsub_rn(__fadd_rn(larea, parea), inter);
    return inter / denom;
}

__device__ __forceinline__ u64 umax64(u64 a, u64 b) { return a > b ? a : b; }

// ---------- 64-lane u64 max butterfly via DPP; result valid in lane 63 ----------
__device__ __forceinline__ u64 dpp_max64(u64 v) {
    unsigned lo, hi; u64 o;
#define DPP_STEP(CTRL) \
    lo = (unsigned)__builtin_amdgcn_update_dpp(0, (int)(unsigned)(v & 0xffffffffull), CTRL, 0xf, 0xf, true); \
    hi = (unsigned)__builtin_amdgcn_update_dpp(0, (int)(unsigned)(v >> 32),           CTRL, 0xf, 0xf, true); \
    o = (((u64)hi) << 32) | lo; \
    if (o > v) v = o;
    DPP_STEP(0x111) DPP_STEP(0x112) DPP_STEP(0x114)
    DPP_STEP(0x118) DPP_STEP(0x142) DPP_STEP(0x143)
#undef DPP_STEP
    return v;
}

__device__ __forceinline__ u64 readlane64(u64 v, int l) {
    unsigned lo = (unsigned)__builtin_amdgcn_readlane((int)(unsigned)(v & 0xffffffffull), l);
    unsigned hi = (unsigned)__builtin_amdgcn_readlane((int)(unsigned)(v >> 32), l);
    return (((u64)hi) << 32) | lo;
}

// =====================================================================================
// Kernel A (parallel, 1024 blocks): initial packed key per row
//   key = (ioubits<<20) | (row<<10) | col ;  0 == dead row (max IoU == 0)
// =====================================================================================
__global__ void __launch_bounds__(64) init_rowmax(const float* __restrict__ labels,
                                                  const float* __restrict__ preds,
                                                  u64* __restrict__ key_ws) {
    const int b = blockIdx.x;
    const int lane = threadIdx.x;
    float4 lb = ((const float4*)labels)[b];
    float larea = __fmul_rn(__fsub_rn(lb.z, lb.x), __fsub_rn(lb.w, lb.y));
    float bv = -1.0f; int bc = 0;
    #pragma unroll
    for (int j = 0; j < 16; ++j) {
        int c = lane + (j << 6);
        float4 pb = ((const float4*)preds)[c];
        float parea = __fmul_rn(__fsub_rn(pb.z, pb.x), __fsub_rn(pb.w, pb.y));
        float v = iou_pair(lb, larea, pb, parea);
        if (v > bv || (v == bv && c > bc)) { bv = v; bc = c; }
    }
    u64 pv = ((u64)__float_as_uint(bv) << 10) | (unsigned)bc;
    pv = dpp_max64(pv);
    if (lane == 63) {
        u64 val = pv >> 10;
        key_ws[b] = val ? ((val << 20) | ((u64)b << 10) | (pv & 1023ull)) : 0ull;
    }
}

// =====================================================================================
// Kernel B: SINGLE-WAVE lazy greedy.
//   Keys in LDS (one u64 per row); per-lane incremental max over its 16 rows.
//   Lazy validation + zero-kill + key-transfer (all exactness-proven in R4/R5).
// =====================================================================================
__global__ void __launch_bounds__(64, 1)
greedy1w(const float* __restrict__ preds,
         const float* __restrict__ labels,
         const u64* __restrict__ key_ws,   // may be null
         float* __restrict__ out) {
    __shared__ float4 pred4s[NBOX];
    __shared__ float4 lab4s[NBOX];
    __shared__ float  parea_s[NBOX];
    __shared__ float  larea_s[NBOX];
    __shared__ u16    perm[NBOX];
    __shared__ u64    klds[NBOX];

    const int lane = (int)threadIdx.x;

    #pragma unroll
    for (int j = 0; j < 16; ++j) {
        int i = lane + (j << 6);
        float4 p = ((const float4*)preds)[i];
        float4 L = ((const float4*)labels)[i];
        pred4s[i] = p;
        lab4s[i]  = L;
        parea_s[i] = __fmul_rn(__fsub_rn(p.z, p.x), __fsub_rn(p.w, p.y));
        larea_s[i] = __fmul_rn(__fsub_rn(L.z, L.x), __fsub_rn(L.w, L.y));
        perm[i] = (u16)i;
        klds[i] = key_ws ? key_ws[i] : 0ull;
    }
    // single wave: LDS ops are in program order; no barrier needed.

    u32 myseen = 0;        // bit j: column (lane + 64j) consumed
    bool dirty = true;     // this lane's m_lane needs refold from klds
    u64 m_lane = 0;        // max over klds[lane + 64j], j=0..15

    // wave-cooperative exact rescan of one (uniform) row over unseen columns.
    // returns packed (val<<20)|(row<<10)|col, or 0 if max IoU == 0 (permanently dead).
    auto rescan = [&](int row) -> u64 {
        int pm = (int)perm[row];
        float4 lb = lab4s[pm];
        float la = larea_s[pm];
        u64 best = 0;
        #pragma unroll
        for (int j2 = 0; j2 < 16; ++j2) {
            int cc = lane + (j2 << 6);
            float v = iou_pair(lb, la, pred4s[cc], parea_s[cc]);
            u64 pv = ((u64)__float_as_uint(v) << 10) | (unsigned)cc;
            if ((myseen >> j2) & 1u) pv = 0;
            best = umax64(best, pv);
        }
        best = dpp_max64(best);
        u64 bm = readlane64(best, 63);
        u64 val = bm >> 10;
        return val ? ((val << 20) | ((u64)(unsigned)row << 10) | (bm & 1023ull)) : 0ull;
    };

    if (!key_ws) {   // fallback init (ws too small): exact in-kernel row maxes
        for (int row = 0; row < NBOX; ++row) {
            u64 nk = rescan(row);
            if (lane == 0) klds[row] = nk;
        }
    }

    // ---- lazy greedy: pick max bound, validate, commit or rescan-and-repick ----
    for (int iter = 0; iter < 8192; ++iter) {
        if (dirty) {            // refold this lane's 16 keys from LDS
            u64 rec = 0;
            #pragma unroll
            for (int j = 0; j < 16; ++j) rec = umax64(rec, klds[lane + (j << 6)]);
            m_lane = rec;
            dirty = false;
        }
        u64 kb = readlane64(dpp_max64(m_lane), 63);
        if ((kb >> 20) == 0ull) break;       // all live true-max == 0 -> perm final
        const int r  = (int)((kb >> 10) & 1023);
        const int c  = (int)(kb & 1023);
        const int jc = c >> 6, lc = c & 63;

        // validate: winner's stored col still unseen?
        u32 sl = (u32)__builtin_amdgcn_readlane((int)myseen, lc);
        if ((sl >> jc) & 1u) {
            u64 nk = rescan(r);              // exact refresh; strictly decreases
            if (lane == 0) klds[r] = nk;
            if (lane == (r & 63)) dirty = true;
            continue;                        // re-pick
        }

        // ---- commit: transfer key c -> r (retag row), kill c, mark col c seen ----
        u64 kc = klds[c];                    // broadcast read
        u64 nk = kc ? ((kc & ~((u64)1023 << 10)) | ((u64)(unsigned)r << 10)) : 0ull;
        int ppr = (int)perm[r], ppc = (int)perm[c];
        if (lane == 0) {
            klds[r] = nk;
            klds[c] = 0ull;                  // wins when r == c (write order)
            perm[r] = (u16)ppc;
            perm[c] = (u16)ppr;
        }
        if (lane == (r & 63)) dirty = true;                              // r always refolds
        if (lane == (c & 63) && (int)((m_lane >> 10) & 1023) == c) dirty = true;  // c only if argmax
        if (lane == lc) myseen |= 1u << jc;
    }

    // ---- loss = mean |labels[perm] - predictions| ----
    float sum = 0.0f;
    #pragma unroll
    for (int j = 0; j < 16; ++j) {
        int i = lane + (j << 6);
        float4 pb = pred4s[i];
        float4 lb = lab4s[perm[i]];
        sum += fabsf(lb.x - pb.x) + fabsf(lb.y - pb.y) +
               fabsf(lb.z - pb.z) + fabsf(lb.w - pb.w);
    }
    for (int off = 32; off > 0; off >>= 1) sum += __shfl_xor(sum, off, 64);
    if (lane == 0) out[0] = sum * (1.0f / 4096.0f);
}

extern "C" void kernel_launch(void* const* d_in, const int* in_sizes, int n_in,
                              void* d_out, int out_size, void* d_ws, size_t ws_size,
                              hipStream_t stream) {
    const float* preds  = (const float*)d_in[0];   // predictions [1024,4]
    const float* labels = (const float*)d_in[1];   // labels      [1024,4]
    float* out = (float*)d_out;

    const size_t key_bytes = NBOX * sizeof(u64);   // 8 KB
    if (d_ws && ws_size >= key_bytes) {
        u64* key_ws = (u64*)d_ws;
        init_rowmax<<<NBOX, 64, 0, stream>>>(labels, preds, key_ws);
        greedy1w<<<1, 64, 0, stream>>>(preds, labels, key_ws, out);
    } else {
        greedy1w<<<1, 64, 0, stream>>>(preds, labels, nullptr, out);
    }
}

// Round 8
// 795.632 us; speedup vs baseline: 3.1593x; 2.6235x over previous
//
#include <hip/hip_runtime.h>
#include <stdint.h>

#define NBOX 1024

typedef unsigned long long u64;
typedef unsigned int u32;
typedef unsigned short u16;
typedef unsigned char u8;

// ---------- bit-exact IoU (matches numpy f32 op-for-op; _rn blocks FMA contraction) ----------
__device__ __forceinline__ float iou_pair(const float4 lb, float larea,
                                          const float4 pb, float parea) {
    float ix1 = fmaxf(lb.x, pb.x);
    float iy1 = fmaxf(lb.y, pb.y);
    float ix2 = fminf(lb.z, pb.z);
    float iy2 = fminf(lb.w, pb.w);
    float w = fmaxf(__fsub_rn(ix2, ix1), 0.0f);
    float h = fmaxf(__fsub_rn(iy2, iy1), 0.0f);
    float inter = __fmul_rn(w, h);
    float denom = __fsub_rn(__fadd_rn(larea, parea), inter);
    return inter / denom;
}

__device__ __forceinline__ u64 umax64(u64 a, u64 b) { return a > b ? a : b; }

// ---------- 64-lane u64 max butterfly via DPP; result valid in lane 63 ----------
__device__ __forceinline__ u64 dpp_max64(u64 v) {
    unsigned lo, hi; u64 o;
#define DPP_STEP(CTRL) \
    lo = (unsigned)__builtin_amdgcn_update_dpp(0, (int)(unsigned)(v & 0xffffffffull), CTRL, 0xf, 0xf, true); \
    hi = (unsigned)__builtin_amdgcn_update_dpp(0, (int)(unsigned)(v >> 32),           CTRL, 0xf, 0xf, true); \
    o = (((u64)hi) << 32) | lo; \
    if (o > v) v = o;
    DPP_STEP(0x111) DPP_STEP(0x112) DPP_STEP(0x114)
    DPP_STEP(0x118) DPP_STEP(0x142) DPP_STEP(0x143)
#undef DPP_STEP
    return v;
}

__device__ __forceinline__ u64 readlane64(u64 v, int l) {
    unsigned lo = (unsigned)__builtin_amdgcn_readlane((int)(unsigned)(v & 0xffffffffull), l);
    unsigned hi = (unsigned)__builtin_amdgcn_readlane((int)(unsigned)(v >> 32), l);
    return (((u64)hi) << 32) | lo;
}

// =====================================================================================
// Kernel A (parallel, 1024 blocks): initial row key per label
//   rkey = (ioubits<<10) | col ;  0 == dead (max IoU == 0)
// =====================================================================================
__global__ void __launch_bounds__(64) init_rowmax(const float* __restrict__ labels,
                                                  const float* __restrict__ preds,
                                                  u64* __restrict__ key_ws) {
    const int b = blockIdx.x;
    const int lane = threadIdx.x;
    float4 lb = ((const float4*)labels)[b];
    float larea = __fmul_rn(__fsub_rn(lb.z, lb.x), __fsub_rn(lb.w, lb.y));
    u64 best = 0;
    #pragma unroll
    for (int j = 0; j < 16; ++j) {
        int c = lane + (j << 6);
        float4 pb = ((const float4*)preds)[c];
        float parea = __fmul_rn(__fsub_rn(pb.z, pb.x), __fsub_rn(pb.w, pb.y));
        float v = iou_pair(lb, larea, pb, parea);
        best = umax64(best, ((u64)__float_as_uint(v) << 10) | (unsigned)c);
    }
    best = dpp_max64(best);
    if (lane == 63) key_ws[b] = (best >> 10) ? best : 0ull;
}

// =====================================================================================
// Kernel B: 16-wave parallel greedy via locally-dominant pairs (== sequential greedy
//   on the fixed JM for distinct values; tie-breaks replicated via (val,pos,label)).
// =====================================================================================
__global__ void __launch_bounds__(1024, 1)
rounds_kernel(const float* __restrict__ preds,
              const float* __restrict__ labels,
              const u64* __restrict__ key_ws,   // may be null
              float* __restrict__ out) {
    __shared__ float4 pred4s[NBOX];
    __shared__ float4 lab4s[NBOX];
    __shared__ float  parea_s[NBOX];
    __shared__ float  larea_s[NBOX];
    __shared__ u64    rkey[NBOX];      // (val<<10)|col ; 0 = dead or locked
    __shared__ u64    colbest[NBOX];   // suitor max: (val<<20)|(pos<<10)|label
    __shared__ u16    pos_s[NBOX];     // label -> current row (for tie-breaks)
    __shared__ u16    dest_s[NBOX];    // committed label -> its col
    __shared__ u16    perm_s[NBOX];    // row -> label (final answer)
    __shared__ u8     seenc[NBOX];     // col consumed
    __shared__ u8     lockedl[NBOX];   // label locked
    __shared__ u32    commits[NBOX];
    __shared__ int    ncommit;
    __shared__ float  fpart[16];

    const int t    = (int)threadIdx.x;   // 0..1023
    const int lane = t & 63;
    const int wid  = t >> 6;             // 0..15

    {
        float4 p = ((const float4*)preds)[t];
        float4 L = ((const float4*)labels)[t];
        pred4s[t] = p;
        lab4s[t]  = L;
        parea_s[t] = __fmul_rn(__fsub_rn(p.z, p.x), __fsub_rn(p.w, p.y));
        larea_s[t] = __fmul_rn(__fsub_rn(L.z, L.x), __fsub_rn(L.w, L.y));
        pos_s[t] = (u16)t; perm_s[t] = (u16)t; dest_s[t] = 0;
        seenc[t] = 0; lockedl[t] = 0;
        rkey[t] = key_ws ? key_ws[t] : 0ull;
        if (t == 0) ncommit = 0;
    }
    __syncthreads();

    // wave-cooperative exact row scan of label L over unseen cols (uniform L per wave)
    auto scan_row = [&](int L) -> u64 {
        float4 lb = lab4s[L];
        float la = larea_s[L];
        u64 best = 0;
        #pragma unroll
        for (int j = 0; j < 16; ++j) {
            int cc = lane + (j << 6);
            float v = iou_pair(lb, la, pred4s[cc], parea_s[cc]);
            u64 pv = ((u64)__float_as_uint(v) << 10) | (unsigned)cc;
            if (seenc[cc]) pv = 0;
            best = umax64(best, pv);
        }
        best = dpp_max64(best);
        u64 bm = readlane64(best, 63);
        return (bm >> 10) ? bm : 0ull;      // ties -> larger col (exact)
    };

    if (!key_ws) {   // fallback init (ws too small)
        for (int L = wid; L < NBOX; L += 16) {
            u64 bm = scan_row(L);
            if (lane == 0) rkey[L] = bm;
        }
        __syncthreads();
    }

    for (int round = 0; round < 2048; ++round) {
        // ---- P0: clear suitor table / counter ----
        colbest[t] = 0ull;
        if (t == 0) ncommit = 0;
        __syncthreads();

        // ---- P1: lazy rescan of labels whose argmax col was consumed ----
        for (int L = wid; L < NBOX; L += 16) {
            u64 k = rkey[L];                     // wave-uniform broadcast
            if (k && seenc[k & 1023ull]) {
                u64 bm = scan_row(L);            // exact (argcol unseen => exact value)
                if (lane == 0) rkey[L] = bm;
            }
        }
        __syncthreads();

        // ---- P2: suitor push (label t -> its argmax col) ----
        {
            u64 k = rkey[t];
            if (k) atomicMax((unsigned long long*)&colbest[k & 1023ull],
                             ((k >> 10) << 20) | ((u64)pos_s[t] << 10) | (u64)(unsigned)t);
        }
        __syncthreads();

        // ---- P3: verify candidate cols (true col-max == suitor -> dominant -> commit) ----
        for (int c = wid; c < NBOX; c += 16) {
            u64 sb = colbest[c];                 // wave-uniform broadcast
            if (!sb) continue;
            float4 pc = pred4s[c];
            float  pa = parea_s[c];
            u64 best = 0;
            #pragma unroll
            for (int j = 0; j < 16; ++j) {
                int L = lane + (j << 6);
                float v = iou_pair(lab4s[L], larea_s[L], pc, pa);
                u64 key = ((u64)__float_as_uint(v) << 20) |
                          ((u64)pos_s[L] << 10) | (unsigned)L;
                if (lockedl[L]) key = 0;
                best = umax64(best, key);
            }
            best = dpp_max64(best);
            u64 cm = readlane64(best, 63);       // ties -> larger pos (exact)
            if ((u32)(cm & 1023ull) == (u32)(sb & 1023ull)) {
                if (lane == 0) {
                    int ix = atomicAdd(&ncommit, 1);
                    commits[ix] = ((u32)c << 16) | (u32)(sb & 1023ull);
                }
            }
        }
        __syncthreads();

        // ---- P4: apply commits (pairwise disjoint labels & cols) ----
        const int nc = ncommit;
        for (int i = t; i < nc; i += 1024) {
            u32 e = commits[i];
            int c = (int)(e >> 16), L = (int)(e & 0xFFFFu);
            seenc[c] = 1; lockedl[L] = 1; rkey[L] = 0ull;
            dest_s[L] = (u16)c; perm_s[c] = (u16)L;
        }
        __syncthreads();

        // ---- P5: chase displacement chains -> pos (tie-breaks) + perm for unseen rows ----
        if (!seenc[t]) {
            int l = t;
            while (lockedl[l]) l = (int)dest_s[l];
            pos_s[l] = (u16)t;
            perm_s[t] = (u16)l;
        }
        __syncthreads();

        if (nc == 0) break;                      // no positive keys left -> perm final
    }

    // ---- loss = mean |labels[perm] - predictions| ----
    {
        float4 lb = lab4s[perm_s[t]];
        float4 pb = pred4s[t];
        float sum = fabsf(lb.x - pb.x) + fabsf(lb.y - pb.y) +
                    fabsf(lb.z - pb.z) + fabsf(lb.w - pb.w);
        for (int off = 32; off > 0; off >>= 1) sum += __shfl_xor(sum, off, 64);
        if (lane == 0) fpart[wid] = sum;
        __syncthreads();
        if (t == 0) {
            float s = 0.0f;
            for (int w = 0; w < 16; ++w) s += fpart[w];
            out[0] = s * (1.0f / 4096.0f);
        }
    }
}

extern "C" void kernel_launch(void* const* d_in, const int* in_sizes, int n_in,
                              void* d_out, int out_size, void* d_ws, size_t ws_size,
                              hipStream_t stream) {
    const float* preds  = (const float*)d_in[0];   // predictions [1024,4]
    const float* labels = (const float*)d_in[1];   // labels      [1024,4]
    float* out = (float*)d_out;

    const size_t key_bytes = NBOX * sizeof(u64);   // 8 KB
    if (d_ws && ws_size >= key_bytes) {
        u64* key_ws = (u64*)d_ws;
        init_rowmax<<<NBOX, 64, 0, stream>>>(labels, preds, key_ws);
        rounds_kernel<<<1, 1024, 0, stream>>>(preds, labels, key_ws, out);
    } else {
        rounds_kernel<<<1, 1024, 0, stream>>>(preds, labels, nullptr, out);
    }
}

// Round 9
// 508.954 us; speedup vs baseline: 4.9388x; 1.5633x over previous
//
#include <hip/hip_runtime.h>
#include <stdint.h>

#define NBOX 1024

typedef unsigned long long u64;
typedef unsigned int u32;
typedef unsigned short u16;
typedef unsigned char u8;

// ---------- bit-exact IoU (matches numpy f32 op-for-op; _rn blocks FMA contraction) ----------
__device__ __forceinline__ float iou_pair(const float4 lb, float larea,
                                          const float4 pb, float parea) {
    float ix1 = fmaxf(lb.x, pb.x);
    float iy1 = fmaxf(lb.y, pb.y);
    float ix2 = fminf(lb.z, pb.z);
    float iy2 = fminf(lb.w, pb.w);
    float w = fmaxf(__fsub_rn(ix2, ix1), 0.0f);
    float h = fmaxf(__fsub_rn(iy2, iy1), 0.0f);
    float inter = __fmul_rn(w, h);
    float denom = __fsub_rn(__fadd_rn(larea, parea), inter);
    return inter / denom;
}

__device__ __forceinline__ u64 umax64(u64 a, u64 b) { return a > b ? a : b; }

// ---------- 64-lane u64 max butterfly via DPP; result valid in lane 63 ----------
__device__ __forceinline__ u64 dpp_max64(u64 v) {
    unsigned lo, hi; u64 o;
#define DPP_STEP(CTRL) \
    lo = (unsigned)__builtin_amdgcn_update_dpp(0, (int)(unsigned)(v & 0xffffffffull), CTRL, 0xf, 0xf, true); \
    hi = (unsigned)__builtin_amdgcn_update_dpp(0, (int)(unsigned)(v >> 32),           CTRL, 0xf, 0xf, true); \
    o = (((u64)hi) << 32) | lo; \
    if (o > v) v = o;
    DPP_STEP(0x111) DPP_STEP(0x112) DPP_STEP(0x114)
    DPP_STEP(0x118) DPP_STEP(0x142) DPP_STEP(0x143)
#undef DPP_STEP
    return v;
}

__device__ __forceinline__ u64 readlane64(u64 v, int l) {
    unsigned lo = (unsigned)__builtin_amdgcn_readlane((int)(unsigned)(v & 0xffffffffull), l);
    unsigned hi = (unsigned)__builtin_amdgcn_readlane((int)(unsigned)(v >> 32), l);
    return (((u64)hi) << 32) | lo;
}

// =====================================================================================
// Init A (1024 blocks): per-label row key = (ioubits<<10)|argcol (tie -> larger col); 0 = dead
// =====================================================================================
__global__ void __launch_bounds__(64) init_rowmax(const float* __restrict__ labels,
                                                  const float* __restrict__ preds,
                                                  u64* __restrict__ rkey_ws) {
    const int b = blockIdx.x;
    const int lane = threadIdx.x;
    float4 lb = ((const float4*)labels)[b];
    float larea = __fmul_rn(__fsub_rn(lb.z, lb.x), __fsub_rn(lb.w, lb.y));
    u64 best = 0;
    #pragma unroll
    for (int j = 0; j < 16; ++j) {
        int c = lane + (j << 6);
        float4 pb = ((const float4*)preds)[c];
        float parea = __fmul_rn(__fsub_rn(pb.z, pb.x), __fsub_rn(pb.w, pb.y));
        float v = iou_pair(lb, larea, pb, parea);
        best = umax64(best, ((u64)__float_as_uint(v) << 10) | (unsigned)c);
    }
    best = dpp_max64(best);
    if (lane == 63) rkey_ws[b] = (best >> 10) ? best : 0ull;
}

// =====================================================================================
// Init B (1024 blocks): per-col bound cub = (valbits<<32)|(tie<<16)|label ; 0 = dead col
//   (initial pos == label, so (val,label) ordering == (val,pos,label); tie = dup top val)
// =====================================================================================
__global__ void __launch_bounds__(64) init_colmax(const float* __restrict__ labels,
                                                  const float* __restrict__ preds,
                                                  u64* __restrict__ cub_ws) {
    const int c = blockIdx.x;
    const int lane = threadIdx.x;
    float4 pc = ((const float4*)preds)[c];
    float pa = __fmul_rn(__fsub_rn(pc.z, pc.x), __fsub_rn(pc.w, pc.y));
    u64 best = 0; u32 v1 = 0, v2 = 0;
    #pragma unroll
    for (int j = 0; j < 16; ++j) {
        int L = lane + (j << 6);
        float4 lb = ((const float4*)labels)[L];
        float la = __fmul_rn(__fsub_rn(lb.z, lb.x), __fsub_rn(lb.w, lb.y));
        float v = iou_pair(lb, la, pc, pa);
        u32 vb = __float_as_uint(v);
        if (vb >= v1) { v2 = v1; v1 = vb; } else { v2 = (vb > v2) ? vb : v2; }
        best = umax64(best, ((u64)vb << 10) | (unsigned)L);
    }
    best = dpp_max64(best);
    u64 bm = readlane64(best, 63);
    u32 V = (u32)(bm >> 10);
    u64 b1 = __ballot(v1 == V);
    u64 b2 = __ballot(v2 == V);
    bool tie = (__popcll(b1) >= 2) || (b2 != 0ull);
    if (lane == 63)
        cub_ws[c] = V ? (((u64)V << 32) | (tie ? (1ull << 16) : 0ull) | (bm & 1023ull))
                      : 0ull;
}

// =====================================================================================
// Main: 16-wave parallel greedy, lazy row keys + lazy column bounds.
// =====================================================================================
__global__ void __launch_bounds__(1024, 1)
rounds_kernel(const float* __restrict__ preds,
              const float* __restrict__ labels,
              const u64* __restrict__ rkey_ws,   // may be null
              const u64* __restrict__ cub_ws,    // may be null
              float* __restrict__ out) {
    __shared__ float4 pred4s[NBOX];
    __shared__ float4 lab4s[NBOX];
    __shared__ float  parea_s[NBOX];
    __shared__ float  larea_s[NBOX];
    __shared__ u64    rkey[NBOX];      // (val<<10)|col ; 0 = dead/locked
    __shared__ u64    cub[NBOX];       // (val<<32)|(tie<<16)|label ; exact while label unlocked & !tie
    __shared__ u64    colbest[NBOX];   // suitor: (val<<20)|(pos<<10)|label
    __shared__ u16    pos_s[NBOX];     // label -> current row
    __shared__ u16    dest_s[NBOX];    // locked label -> its col
    __shared__ u16    perm_s[NBOX];    // row -> label
    __shared__ u8     seenc[NBOX];
    __shared__ u8     lockedl[NBOX];
    __shared__ u16    rowq[NBOX];
    __shared__ u16    colq[NBOX];
    __shared__ u32    commits[NBOX];
    __shared__ int    nrowq, ncolq, ncommit;
    __shared__ float  fpart[16];

    const int t    = (int)threadIdx.x;   // 0..1023
    const int lane = t & 63;
    const int wid  = t >> 6;             // 0..15

    {
        float4 p = ((const float4*)preds)[t];
        float4 L = ((const float4*)labels)[t];
        pred4s[t] = p;
        lab4s[t]  = L;
        parea_s[t] = __fmul_rn(__fsub_rn(p.z, p.x), __fsub_rn(p.w, p.y));
        larea_s[t] = __fmul_rn(__fsub_rn(L.z, L.x), __fsub_rn(L.w, L.y));
        pos_s[t] = (u16)t; perm_s[t] = (u16)t; dest_s[t] = 0;
        seenc[t] = 0; lockedl[t] = 0;
        rkey[t] = rkey_ws ? rkey_ws[t] : 0ull;
        cub[t]  = cub_ws  ? cub_ws[t]  : 0ull;
        if (t == 0) { nrowq = 0; ncolq = 0; ncommit = 0; }
    }
    __syncthreads();

    // wave-cooperative exact row scan of label L over unseen cols (tie -> larger col)
    auto scan_row = [&](int L) -> u64 {
        float4 lb = lab4s[L];
        float la = larea_s[L];
        u64 best = 0;
        #pragma unroll
        for (int j = 0; j < 16; ++j) {
            int cc = lane + (j << 6);
            float v = iou_pair(lb, la, pred4s[cc], parea_s[cc]);
            u64 pv = ((u64)__float_as_uint(v) << 10) | (unsigned)cc;
            if (seenc[cc]) pv = 0;
            best = umax64(best, pv);
        }
        best = dpp_max64(best);
        u64 bm = readlane64(best, 63);
        return (bm >> 10) ? bm : 0ull;
    };

    // wave-cooperative exact col scan over unlocked labels (tie -> larger CURRENT pos);
    // returns cub format with tie flag.
    auto scan_col = [&](int c) -> u64 {
        float4 pc = pred4s[c];
        float  pa = parea_s[c];
        u64 best = 0; u32 v1 = 0, v2 = 0;
        #pragma unroll
        for (int j = 0; j < 16; ++j) {
            int L = lane + (j << 6);
            float v = iou_pair(lab4s[L], larea_s[L], pc, pa);
            u32 vb = __float_as_uint(v);
            if (lockedl[L]) vb = 0;
            if (vb >= v1) { v2 = v1; v1 = vb; } else { v2 = (vb > v2) ? vb : v2; }
            u64 key = ((u64)vb << 20) | ((u64)pos_s[L] << 10) | (unsigned)L;
            if (!vb) key = 0;
            best = umax64(best, key);
        }
        best = dpp_max64(best);
        u64 bm = readlane64(best, 63);
        u32 V = (u32)(bm >> 20);
        u64 b1 = __ballot(v1 == V);
        u64 b2 = __ballot(v2 == V);
        bool tie = (__popcll(b1) >= 2) || (b2 != 0ull);
        return V ? (((u64)V << 32) | (tie ? (1ull << 16) : 0ull) | (bm & 1023ull)) : 0ull;
    };

    if (!rkey_ws) {   // fallback init (ws too small)
        for (int L = wid; L < NBOX; L += 16) {
            u64 bm = scan_row(L);
            if (lane == 0) rkey[L] = bm;
        }
        for (int c = wid; c < NBOX; c += 16) {
            u64 cb = scan_col(c);
            if (lane == 0) cub[c] = cb;
        }
        __syncthreads();
    }

    for (int round = 0; round < 2048; ++round) {
        // ---- A: clear suitors; build row-rescan queue; reset counters ----
        colbest[t] = 0ull;
        {
            u64 k = rkey[t];
            if (k && seenc[k & 1023ull]) { int ix = atomicAdd(&nrowq, 1); rowq[ix] = (u16)t; }
        }
        if (t == 0) { ncolq = 0; ncommit = 0; }
        __syncthreads();

        // ---- B: row rescans (wave-cooperative) ----
        {
            const int nq = nrowq;
            for (int i = wid; i < nq; i += 16) {
                int L = rowq[i];
                u64 bm = scan_row(L);
                if (lane == 0) rkey[L] = bm;
            }
        }
        __syncthreads();

        // ---- C: suitor push ----
        {
            u64 k = rkey[t];
            if (k) atomicMax((unsigned long long*)&colbest[k & 1023ull],
                             ((k >> 10) << 20) | ((u64)pos_s[t] << 10) | (u64)(unsigned)t);
        }
        __syncthreads();

        // ---- D: per-col fast check: commit via cached bound, or queue rescan ----
        {
            u64 sb = colbest[t];
            if (sb) {
                u32 sval = (u32)(sb >> 20);
                u32 slab = (u32)(sb & 1023ull);
                u64 cb = cub[t];
                u32 cval = (u32)(cb >> 32);
                u32 clab = (u32)(cb & 1023ull);
                bool ctie = (cb >> 16) & 1ull;
                if (lockedl[clab] || ctie || (sval == cval && slab != clab)) {
                    int ix = atomicAdd(&ncolq, 1); colq[ix] = (u16)t;   // needs fresh scan
                } else if (slab == clab) {                               // dominant, commit
                    int ix = atomicAdd(&ncommit, 1);
                    commits[ix] = ((u32)t << 16) | slab;
                } // else sval < cval: suitor provably not col-max -> no commit this round
            }
        }
        __syncthreads();

        // ---- E: col rescans (wave-cooperative), refresh bounds ----
        {
            const int nq = ncolq;
            for (int i = wid; i < nq; i += 16) {
                int c = colq[i];
                u64 cb = scan_col(c);
                if (lane == 0) cub[c] = cb;
            }
        }
        __syncthreads();

        // ---- F: re-check rescanned cols (bound now exact w/ current pos) ----
        {
            const int nq = ncolq;
            for (int i = t; i < nq; i += 1024) {
                int c = colq[i];
                u64 sb = colbest[c];
                u64 cb = cub[c];
                if (sb && cb && (u32)(cb & 1023ull) == (u32)(sb & 1023ull)) {
                    int ix = atomicAdd(&ncommit, 1);
                    commits[ix] = ((u32)c << 16) | (u32)(sb & 1023ull);
                }
            }
        }
        __syncthreads();

        // ---- G: apply commits (disjoint labels & cols) ----
        const int nc = ncommit;
        for (int i = t; i < nc; i += 1024) {
            u32 e = commits[i];
            int c = (int)(e >> 16), L = (int)(e & 0xFFFFu);
            seenc[c] = 1; lockedl[L] = 1; rkey[L] = 0ull;
            dest_s[L] = (u16)c; perm_s[c] = (u16)L;
        }
        if (t == 0) nrowq = 0;
        __syncthreads();

        // ---- H: chase displacement chains -> pos (tie-breaks) + perm for open rows ----
        if (!seenc[t]) {
            int l = t;
            while (lockedl[l]) l = (int)dest_s[l];
            pos_s[l] = (u16)t;
            perm_s[t] = (u16)l;
        }
        __syncthreads();

        if (nc == 0) break;                      // no live positive keys -> perm final
    }

    // ---- loss = mean |labels[perm] - predictions| ----
    {
        float4 lb = lab4s[perm_s[t]];
        float4 pb = pred4s[t];
        float sum = fabsf(lb.x - pb.x) + fabsf(lb.y - pb.y) +
                    fabsf(lb.z - pb.z) + fabsf(lb.w - pb.w);
        for (int off = 32; off > 0; off >>= 1) sum += __shfl_xor(sum, off, 64);
        if (lane == 0) fpart[wid] = sum;
        __syncthreads();
        if (t == 0) {
            float s = 0.0f;
            for (int w = 0; w < 16; ++w) s += fpart[w];
            out[0] = s * (1.0f / 4096.0f);
        }
    }
}

extern "C" void kernel_launch(void* const* d_in, const int* in_sizes, int n_in,
                              void* d_out, int out_size, void* d_ws, size_t ws_size,
                              hipStream_t stream) {
    const float* preds  = (const float*)d_in[0];   // predictions [1024,4]
    const float* labels = (const float*)d_in[1];   // labels      [1024,4]
    float* out = (float*)d_out;

    const size_t need = 2 * NBOX * sizeof(u64);    // rkey (8 KB) + cub (8 KB)
    if (d_ws && ws_size >= need) {
        u64* rkey_ws = (u64*)d_ws;
        u64* cub_ws  = (u64*)((char*)d_ws + NBOX * sizeof(u64));
        init_rowmax<<<NBOX, 64, 0, stream>>>(labels, preds, rkey_ws);
        init_colmax<<<NBOX, 64, 0, stream>>>(labels, preds, cub_ws);
        rounds_kernel<<<1, 1024, 0, stream>>>(preds, labels, rkey_ws, cub_ws, out);
    } else {
        rounds_kernel<<<1, 1024, 0, stream>>>(preds, labels, nullptr, nullptr, out);
    }
}

// Round 10
// 502.316 us; speedup vs baseline: 5.0041x; 1.0132x over previous
//
#include <hip/hip_runtime.h>
#include <stdint.h>

#define NBOX 1024

typedef unsigned long long u64;
typedef unsigned int u32;
typedef unsigned short u16;
typedef unsigned char u8;

// ---------- bit-exact IoU (matches numpy f32 op-for-op; _rn blocks FMA contraction) ----------
__device__ __forceinline__ float iou_pair(const float4 lb, float larea,
                                          const float4 pb, float parea) {
    float ix1 = fmaxf(lb.x, pb.x);
    float iy1 = fmaxf(lb.y, pb.y);
    float ix2 = fminf(lb.z, pb.z);
    float iy2 = fminf(lb.w, pb.w);
    float w = fmaxf(__fsub_rn(ix2, ix1), 0.0f);
    float h = fmaxf(__fsub_rn(iy2, iy1), 0.0f);
    float inter = __fmul_rn(w, h);
    float denom = __fsub_rn(__fadd_rn(larea, parea), inter);
    return inter / denom;
}

__device__ __forceinline__ u64 umax64(u64 a, u64 b) { return a > b ? a : b; }

// ---------- 64-lane u64 max butterfly via DPP; result valid in lane 63 ----------
__device__ __forceinline__ u64 dpp_max64(u64 v) {
    unsigned lo, hi; u64 o;
#define DPP_STEP(CTRL) \
    lo = (unsigned)__builtin_amdgcn_update_dpp(0, (int)(unsigned)(v & 0xffffffffull), CTRL, 0xf, 0xf, true); \
    hi = (unsigned)__builtin_amdgcn_update_dpp(0, (int)(unsigned)(v >> 32),           CTRL, 0xf, 0xf, true); \
    o = (((u64)hi) << 32) | lo; \
    if (o > v) v = o;
    DPP_STEP(0x111) DPP_STEP(0x112) DPP_STEP(0x114)
    DPP_STEP(0x118) DPP_STEP(0x142) DPP_STEP(0x143)
#undef DPP_STEP
    return v;
}

__device__ __forceinline__ u64 readlane64(u64 v, int l) {
    unsigned lo = (unsigned)__builtin_amdgcn_readlane((int)(unsigned)(v & 0xffffffffull), l);
    unsigned hi = (unsigned)__builtin_amdgcn_readlane((int)(unsigned)(v >> 32), l);
    return (((u64)hi) << 32) | lo;
}

// =====================================================================================
// Init A (1024 blocks): per-label row key = (ioubits<<10)|argcol (tie -> larger col); 0 = dead
// =====================================================================================
__global__ void __launch_bounds__(64) init_rowmax(const float* __restrict__ labels,
                                                  const float* __restrict__ preds,
                                                  u64* __restrict__ rkey_ws) {
    const int b = blockIdx.x;
    const int lane = threadIdx.x;
    float4 lb = ((const float4*)labels)[b];
    float larea = __fmul_rn(__fsub_rn(lb.z, lb.x), __fsub_rn(lb.w, lb.y));
    u64 best = 0;
    #pragma unroll
    for (int j = 0; j < 16; ++j) {
        int c = lane + (j << 6);
        float4 pb = ((const float4*)preds)[c];
        float parea = __fmul_rn(__fsub_rn(pb.z, pb.x), __fsub_rn(pb.w, pb.y));
        float v = iou_pair(lb, larea, pb, parea);
        best = umax64(best, ((u64)__float_as_uint(v) << 10) | (unsigned)c);
    }
    best = dpp_max64(best);
    if (lane == 63) rkey_ws[b] = (best >> 10) ? best : 0ull;
}

// =====================================================================================
// Init B (1024 blocks): per-col bound cub = (valbits<<32)|(tie<<16)|label ; 0 = dead col
// =====================================================================================
__global__ void __launch_bounds__(64) init_colmax(const float* __restrict__ labels,
                                                  const float* __restrict__ preds,
                                                  u64* __restrict__ cub_ws) {
    const int c = blockIdx.x;
    const int lane = threadIdx.x;
    float4 pc = ((const float4*)preds)[c];
    float pa = __fmul_rn(__fsub_rn(pc.z, pc.x), __fsub_rn(pc.w, pc.y));
    u64 best = 0; u32 v1 = 0, v2 = 0;
    #pragma unroll
    for (int j = 0; j < 16; ++j) {
        int L = lane + (j << 6);
        float4 lb = ((const float4*)labels)[L];
        float la = __fmul_rn(__fsub_rn(lb.z, lb.x), __fsub_rn(lb.w, lb.y));
        float v = iou_pair(lb, la, pc, pa);
        u32 vb = __float_as_uint(v);
        if (vb >= v1) { v2 = v1; v1 = vb; } else { v2 = (vb > v2) ? vb : v2; }
        best = umax64(best, ((u64)vb << 10) | (unsigned)L);
    }
    best = dpp_max64(best);
    u64 bm = readlane64(best, 63);
    u32 V = (u32)(bm >> 10);
    u64 b1 = __ballot(v1 == V);
    u64 b2 = __ballot(v2 == V);
    bool tie = (__popcll(b1) >= 2) || (b2 != 0ull);
    if (lane == 63)
        cub_ws[c] = V ? (((u64)V << 32) | (tie ? (1ull << 16) : 0ull) | (bm & 1023ull))
                      : 0ull;
}

// =====================================================================================
// Main: 16-wave parallel greedy, lazy row keys + lazy col bounds + compressed chains.
// =====================================================================================
__global__ void __launch_bounds__(1024, 1)
rounds_kernel(const float* __restrict__ preds,
              const float* __restrict__ labels,
              const u64* __restrict__ rkey_ws,   // may be null
              const u64* __restrict__ cub_ws,    // may be null
              float* __restrict__ out) {
    __shared__ float4 pred4s[NBOX];
    __shared__ float4 lab4s[NBOX];
    __shared__ float  parea_s[NBOX];
    __shared__ float  larea_s[NBOX];
    __shared__ u64    rkey[NBOX];      // (val<<10)|col ; 0 = dead/locked
    __shared__ u64    cub[NBOX];       // (val<<32)|(tie<<16)|label ; exact while label unlocked & !tie
    __shared__ u64    colbest[NBOX];   // suitor: (val<<20)|(pos<<10)|label
    __shared__ u16    pos_s[NBOX];     // label -> current row
    __shared__ u16    dest_s[NBOX];    // locked label -> its col (append-only)
    __shared__ u16    perm_s[NBOX];    // row -> label (compressed chase cache / final answer)
    __shared__ u8     seenc[NBOX];
    __shared__ u8     lockedl[NBOX];
    __shared__ u16    rowq[NBOX];
    __shared__ u16    colq[NBOX];
    __shared__ u32    commits[NBOX];
    __shared__ int    nrowq, ncolq, ncommit;
    __shared__ float  fpart[16];

    const int t    = (int)threadIdx.x;   // 0..1023
    const int lane = t & 63;
    const int wid  = t >> 6;             // 0..15

    {
        float4 p = ((const float4*)preds)[t];
        float4 L = ((const float4*)labels)[t];
        pred4s[t] = p;
        lab4s[t]  = L;
        parea_s[t] = __fmul_rn(__fsub_rn(p.z, p.x), __fsub_rn(p.w, p.y));
        larea_s[t] = __fmul_rn(__fsub_rn(L.z, L.x), __fsub_rn(L.w, L.y));
        pos_s[t] = (u16)t; perm_s[t] = (u16)t; dest_s[t] = 0;
        seenc[t] = 0; lockedl[t] = 0;
        rkey[t] = rkey_ws ? rkey_ws[t] : 0ull;
        cub[t]  = cub_ws  ? cub_ws[t]  : 0ull;
        colbest[t] = 0ull;
        if (t == 0) { nrowq = 0; ncolq = 0; ncommit = 0; }
    }
    __syncthreads();

    // wave-cooperative exact row scan of label L over unseen cols (tie -> larger col)
    auto scan_row = [&](int L) -> u64 {
        float4 lb = lab4s[L];
        float la = larea_s[L];
        u64 best = 0;
        #pragma unroll
        for (int j = 0; j < 16; ++j) {
            int cc = lane + (j << 6);
            float v = iou_pair(lb, la, pred4s[cc], parea_s[cc]);
            u64 pv = ((u64)__float_as_uint(v) << 10) | (unsigned)cc;
            if (seenc[cc]) pv = 0;
            best = umax64(best, pv);
        }
        best = dpp_max64(best);
        u64 bm = readlane64(best, 63);
        return (bm >> 10) ? bm : 0ull;
    };

    // wave-cooperative exact col scan over unlocked labels (tie -> larger CURRENT pos)
    auto scan_col = [&](int c) -> u64 {
        float4 pc = pred4s[c];
        float  pa = parea_s[c];
        u64 best = 0; u32 v1 = 0, v2 = 0;
        #pragma unroll
        for (int j = 0; j < 16; ++j) {
            int L = lane + (j << 6);
            float v = iou_pair(lab4s[L], larea_s[L], pc, pa);
            u32 vb = __float_as_uint(v);
            if (lockedl[L]) vb = 0;
            if (vb >= v1) { v2 = v1; v1 = vb; } else { v2 = (vb > v2) ? vb : v2; }
            u64 key = ((u64)vb << 20) | ((u64)pos_s[L] << 10) | (unsigned)L;
            if (!vb) key = 0;
            best = umax64(best, key);
        }
        best = dpp_max64(best);
        u64 bm = readlane64(best, 63);
        u32 V = (u32)(bm >> 20);
        u64 b1 = __ballot(v1 == V);
        u64 b2 = __ballot(v2 == V);
        bool tie = (__popcll(b1) >= 2) || (b2 != 0ull);
        return V ? (((u64)V << 32) | (tie ? (1ull << 16) : 0ull) | (bm & 1023ull)) : 0ull;
    };

    if (!rkey_ws) {   // fallback init (ws too small)
        for (int L = wid; L < NBOX; L += 16) {
            u64 bm = scan_row(L);
            if (lane == 0) rkey[L] = bm;
        }
        for (int c = wid; c < NBOX; c += 16) {
            u64 cb = scan_col(c);
            if (lane == 0) cub[c] = cb;
        }
        __syncthreads();
    }

    for (int round = 0; round < 2048; ++round) {
        // ---- B: row rescans (wave-cooperative) ----
        {
            const int nq = nrowq;
            for (int i = wid; i < nq; i += 16) {
                int L = rowq[i];
                u64 bm = scan_row(L);
                if (lane == 0) rkey[L] = bm;
            }
        }
        __syncthreads();

        // ---- C: suitor push ----
        {
            u64 k = rkey[t];
            if (k) atomicMax((unsigned long long*)&colbest[k & 1023ull],
                             ((k >> 10) << 20) | ((u64)pos_s[t] << 10) | (u64)(unsigned)t);
        }
        __syncthreads();

        // ---- D: per-col fast check via cached bound ----
        {
            u64 sb = colbest[t];
            if (sb) {
                u32 sval = (u32)(sb >> 20);
                u32 slab = (u32)(sb & 1023ull);
                u64 cb = cub[t];
                u32 cval = (u32)(cb >> 32);
                u32 clab = (u32)(cb & 1023ull);
                bool ctie = (cb >> 16) & 1ull;
                if (lockedl[clab] || ctie || (sval == cval && slab != clab)) {
                    int ix = atomicAdd(&ncolq, 1); colq[ix] = (u16)t;   // needs fresh scan
                } else if (slab == clab) {                               // dominant, commit
                    int ix = atomicAdd(&ncommit, 1);
                    commits[ix] = ((u32)t << 16) | slab;
                } // else sval < cval: provably not col-max this round
            }
        }
        __syncthreads();

        // ---- E: col rescans (wave-cooperative), refresh bounds ----
        {
            const int nq = ncolq;
            for (int i = wid; i < nq; i += 16) {
                int c = colq[i];
                u64 cb = scan_col(c);
                if (lane == 0) cub[c] = cb;
            }
        }
        __syncthreads();

        // ---- F: re-check rescanned cols (bound now exact w/ current pos) ----
        {
            const int nq = ncolq;
            for (int i = t; i < nq; i += 1024) {
                int c = colq[i];
                u64 sb = colbest[c];
                u64 cb = cub[c];
                if (sb && cb && (u32)(cb & 1023ull) == (u32)(sb & 1023ull)) {
                    int ix = atomicAdd(&ncommit, 1);
                    commits[ix] = ((u32)c << 16) | (u32)(sb & 1023ull);
                }
            }
        }
        __syncthreads();

        // ---- G: apply commits (disjoint labels & cols) + reset counters ----
        const int nc = ncommit;
        for (int i = t; i < nc; i += 1024) {
            u32 e = commits[i];
            int c = (int)(e >> 16), L = (int)(e & 0xFFFFu);
            seenc[c] = 1; lockedl[L] = 1; rkey[L] = 0ull;
            dest_s[L] = (u16)c; perm_s[c] = (u16)L;
        }
        if (t == 0) { nrowq = 0; ncolq = 0; ncommit = 0; }
        __syncthreads();

        // ---- H: compressed chain chase + next-round prep (clear suitors, build rowq) ----
        colbest[t] = 0ull;
        {
            u64 k = rkey[t];
            if (k && seenc[k & 1023ull]) { int ix = atomicAdd(&nrowq, 1); rowq[ix] = (u16)t; }
        }
        if (!seenc[t]) {
            int l = (int)perm_s[t];              // resume from last round's endpoint
            while (lockedl[l]) l = (int)dest_s[l];
            pos_s[l] = (u16)t;
            perm_s[t] = (u16)l;
        }
        __syncthreads();

        if (nc == 0) break;                      // no live positive keys -> perm final
    }

    // ---- loss = mean |labels[perm] - predictions| ----
    {
        float4 lb = lab4s[perm_s[t]];
        float4 pb = pred4s[t];
        float sum = fabsf(lb.x - pb.x) + fabsf(lb.y - pb.y) +
                    fabsf(lb.z - pb.z) + fabsf(lb.w - pb.w);
        for (int off = 32; off > 0; off >>= 1) sum += __shfl_xor(sum, off, 64);
        if (lane == 0) fpart[wid] = sum;
        __syncthreads();
        if (t == 0) {
            float s = 0.0f;
            for (int w = 0; w < 16; ++w) s += fpart[w];
            out[0] = s * (1.0f / 4096.0f);
        }
    }
}

extern "C" void kernel_launch(void* const* d_in, const int* in_sizes, int n_in,
                              void* d_out, int out_size, void* d_ws, size_t ws_size,
                              hipStream_t stream) {
    const float* preds  = (const float*)d_in[0];   // predictions [1024,4]
    const float* labels = (const float*)d_in[1];   // labels      [1024,4]
    float* out = (float*)d_out;

    const size_t need = 2 * NBOX * sizeof(u64);    // rkey (8 KB) + cub (8 KB)
    if (d_ws && ws_size >= need) {
        u64* rkey_ws = (u64*)d_ws;
        u64* cub_ws  = (u64*)((char*)d_ws + NBOX * sizeof(u64));
        init_rowmax<<<NBOX, 64, 0, stream>>>(labels, preds, rkey_ws);
        init_colmax<<<NBOX, 64, 0, stream>>>(labels, preds, cub_ws);
        rounds_kernel<<<1, 1024, 0, stream>>>(preds, labels, rkey_ws, cub_ws, out);
    } else {
        rounds_kernel<<<1, 1024, 0, stream>>>(preds, labels, nullptr, nullptr, out);
    }
}

// Round 11
// 325.358 us; speedup vs baseline: 7.7258x; 1.5439x over previous
//
#include <hip/hip_runtime.h>
#include <stdint.h>

#define NBOX 1024
#define UNK  0xFFFFFFFFFFFFFFFFull

typedef unsigned long long u64;
typedef unsigned int u32;
typedef unsigned short u16;
typedef unsigned char u8;

// ---------- bit-exact IoU (matches numpy f32 op-for-op; _rn blocks FMA contraction) ----------
__device__ __forceinline__ float iou_pair(const float4 lb, float larea,
                                          const float4 pb, float parea) {
    float ix1 = fmaxf(lb.x, pb.x);
    float iy1 = fmaxf(lb.y, pb.y);
    float ix2 = fminf(lb.z, pb.z);
    float iy2 = fminf(lb.w, pb.w);
    float w = fmaxf(__fsub_rn(ix2, ix1), 0.0f);
    float h = fmaxf(__fsub_rn(iy2, iy1), 0.0f);
    float inter = __fmul_rn(w, h);
    float denom = __fsub_rn(__fadd_rn(larea, parea), inter);
    return inter / denom;
}

__device__ __forceinline__ u64 umax64(u64 a, u64 b) { return a > b ? a : b; }
__device__ __forceinline__ u64 umin64(u64 a, u64 b) { return a < b ? a : b; }

// ---------- 64-lane u64 max butterfly via DPP; result valid in lane 63 ----------
__device__ __forceinline__ u64 dpp_max64(u64 v) {
    unsigned lo, hi; u64 o;
#define DPP_STEP(CTRL) \
    lo = (unsigned)__builtin_amdgcn_update_dpp(0, (int)(unsigned)(v & 0xffffffffull), CTRL, 0xf, 0xf, true); \
    hi = (unsigned)__builtin_amdgcn_update_dpp(0, (int)(unsigned)(v >> 32),           CTRL, 0xf, 0xf, true); \
    o = (((u64)hi) << 32) | lo; \
    if (o > v) v = o;
    DPP_STEP(0x111) DPP_STEP(0x112) DPP_STEP(0x114)
    DPP_STEP(0x118) DPP_STEP(0x142) DPP_STEP(0x143)
#undef DPP_STEP
    return v;
}

// ---------- 64-lane top-2 reduce (distinct packed keys); result valid in lane 63 ----------
__device__ __forceinline__ void dpp_top2(u64 &a1, u64 &a2) {
    unsigned lo, hi; u64 b1, b2, min1;
#define T2STEP(CTRL) \
    lo = (unsigned)__builtin_amdgcn_update_dpp(0, (int)(unsigned)(a1 & 0xffffffffull), CTRL, 0xf, 0xf, true); \
    hi = (unsigned)__builtin_amdgcn_update_dpp(0, (int)(unsigned)(a1 >> 32),           CTRL, 0xf, 0xf, true); \
    b1 = (((u64)hi) << 32) | lo; \
    lo = (unsigned)__builtin_amdgcn_update_dpp(0, (int)(unsigned)(a2 & 0xffffffffull), CTRL, 0xf, 0xf, true); \
    hi = (unsigned)__builtin_amdgcn_update_dpp(0, (int)(unsigned)(a2 >> 32),           CTRL, 0xf, 0xf, true); \
    b2 = (((u64)hi) << 32) | lo; \
    min1 = (b1 == a1) ? 0ull : umin64(a1, b1); \
    a1 = umax64(a1, b1); \
    a2 = umax64(umax64(a2, b2), min1);
    T2STEP(0x111) T2STEP(0x112) T2STEP(0x114) T2STEP(0x118) T2STEP(0x142) T2STEP(0x143)
#undef T2STEP
}

__device__ __forceinline__ u64 readlane64(u64 v, int l) {
    unsigned lo = (unsigned)__builtin_amdgcn_readlane((int)(unsigned)(v & 0xffffffffull), l);
    unsigned hi = (unsigned)__builtin_amdgcn_readlane((int)(unsigned)(v >> 32), l);
    return (((u64)hi) << 32) | lo;
}

// =====================================================================================
// Init A (1024 blocks): writes JM row b, JMT column b, and top-2 row keys for label b.
//   rkey  = (ioubits<<10)|argcol (tie -> larger col); 0 = dead
//   rkey2 = exact second-best (max over cols minus argcol); 0 = dead-after-first
// =====================================================================================
__global__ void __launch_bounds__(64) jm_init(const float* __restrict__ labels,
                                              const float* __restrict__ preds,
                                              float* __restrict__ JM,      // may be null
                                              float* __restrict__ JMT,     // may be null
                                              u64* __restrict__ rkey_ws,
                                              u64* __restrict__ rkey2_ws) {
    const int b = blockIdx.x;
    const int lane = threadIdx.x;
    float4 lb = ((const float4*)labels)[b];
    float la = __fmul_rn(__fsub_rn(lb.z, lb.x), __fsub_rn(lb.w, lb.y));
    u64 a1 = 0, a2 = 0;
    #pragma unroll
    for (int m = 0; m < 4; ++m) {
        float4 v;
        float* vv = (float*)&v;
        #pragma unroll
        for (int k = 0; k < 4; ++k) {
            int c = 4 * lane + 256 * m + k;
            float4 pb = ((const float4*)preds)[c];
            float pa = __fmul_rn(__fsub_rn(pb.z, pb.x), __fsub_rn(pb.w, pb.y));
            vv[k] = iou_pair(lb, la, pb, pa);
        }
        if (JM)  ((float4*)JM)[b * 256 + lane + 64 * m] = v;
        if (JMT) {
            #pragma unroll
            for (int k = 0; k < 4; ++k) {
                int c = 4 * lane + 256 * m + k;
                JMT[(size_t)c * NBOX + b] = vv[k];
            }
        }
        #pragma unroll
        for (int k = 0; k < 4; ++k) {
            int c = 4 * lane + 256 * m + k;
            u64 p = ((u64)__float_as_uint(vv[k]) << 10) | (unsigned)c;
            a2 = umax64(a2, umin64(a1, p));
            a1 = umax64(a1, p);
        }
    }
    dpp_top2(a1, a2);
    if (lane == 63) {
        if ((a1 >> 10) == 0ull) { rkey_ws[b] = 0ull; rkey2_ws[b] = 0ull; }
        else { rkey_ws[b] = a1; rkey2_ws[b] = (a2 >> 10) ? a2 : 0ull; }
    }
}

// =====================================================================================
// Init B (1024 blocks): per-col bound cub = (valbits<<32)|(tie<<16)|label ; 0 = dead col
// =====================================================================================
__global__ void __launch_bounds__(64) init_colmax(const float* __restrict__ labels,
                                                  const float* __restrict__ preds,
                                                  u64* __restrict__ cub_ws) {
    const int c = blockIdx.x;
    const int lane = threadIdx.x;
    float4 pc = ((const float4*)preds)[c];
    float pa = __fmul_rn(__fsub_rn(pc.z, pc.x), __fsub_rn(pc.w, pc.y));
    u64 best = 0; u32 v1 = 0, v2 = 0;
    #pragma unroll
    for (int j = 0; j < 16; ++j) {
        int L = lane + (j << 6);
        float4 lb = ((const float4*)labels)[L];
        float la = __fmul_rn(__fsub_rn(lb.z, lb.x), __fsub_rn(lb.w, lb.y));
        float v = iou_pair(lb, la, pc, pa);
        u32 vb = __float_as_uint(v);
        if (vb >= v1) { v2 = v1; v1 = vb; } else { v2 = (vb > v2) ? vb : v2; }
        best = umax64(best, ((u64)vb << 10) | (unsigned)L);
    }
    best = dpp_max64(best);
    u64 bm = readlane64(best, 63);
    u32 V = (u32)(bm >> 10);
    u64 b1 = __ballot(v1 == V);
    u64 b2 = __ballot(v2 == V);
    bool tie = (__popcll(b1) >= 2) || (b2 != 0ull);
    if (lane == 63)
        cub_ws[c] = V ? (((u64)V << 32) | (tie ? (1ull << 16) : 0ull) | (bm & 1023ull))
                      : 0ull;
}

// =====================================================================================
// Main: 16-wave parallel greedy; JM-fed scans, register masks, top-2 row promotion.
// =====================================================================================
__global__ void __launch_bounds__(1024, 1)
rounds_kernel(const float* __restrict__ preds,
              const float* __restrict__ labels,
              const float* __restrict__ JM,      // may be null
              const float* __restrict__ JMT,     // may be null
              const u64* __restrict__ rkey_ws,   // may be null (then all ws null)
              const u64* __restrict__ rkey2_ws,
              const u64* __restrict__ cub_ws,
              float* __restrict__ out) {
    __shared__ float4 pred4s[NBOX];
    __shared__ float4 lab4s[NBOX];
    __shared__ float  parea_s[NBOX];
    __shared__ float  larea_s[NBOX];
    __shared__ u64    rkey[NBOX];      // (val<<10)|col ; 0 = dead/locked
    __shared__ u64    rkey2[NBOX];     // exact second / 0 dead / UNK unknown
    __shared__ u64    cub[NBOX];       // (val<<32)|(tie<<16)|label
    __shared__ u64    colbest[NBOX];   // suitor: (val<<20)|(pos<<10)|label
    __shared__ u16    pos_s[NBOX];
    __shared__ u16    dest_s[NBOX];
    __shared__ u16    perm_s[NBOX];
    __shared__ u8     seenc[NBOX];
    __shared__ u8     lockedl[NBOX];
    __shared__ u16    rowq[NBOX];
    __shared__ u16    colq[NBOX];
    __shared__ u32    commits[NBOX];
    __shared__ int    nrowq, ncolq, ncommit;
    __shared__ float  fpart[16];

    const int t    = (int)threadIdx.x;
    const int lane = t & 63;
    const int wid  = t >> 6;

    {
        float4 p = ((const float4*)preds)[t];
        float4 L = ((const float4*)labels)[t];
        pred4s[t] = p;
        lab4s[t]  = L;
        parea_s[t] = __fmul_rn(__fsub_rn(p.z, p.x), __fsub_rn(p.w, p.y));
        larea_s[t] = __fmul_rn(__fsub_rn(L.z, L.x), __fsub_rn(L.w, L.y));
        pos_s[t] = (u16)t; perm_s[t] = (u16)t; dest_s[t] = 0;
        seenc[t] = 0; lockedl[t] = 0;
        rkey[t]  = rkey_ws  ? rkey_ws[t]  : 0ull;
        rkey2[t] = rkey2_ws ? rkey2_ws[t] : UNK;
        cub[t]   = cub_ws   ? cub_ws[t]   : 0ull;
        colbest[t] = 0ull;
        if (t == 0) { nrowq = 0; ncolq = 0; ncommit = 0; }
    }
    __syncthreads();

    u32 myseen = 0;    // bit (m<<2)|k : col 4*lane+256m+k consumed
    u32 mylocked = 0;  // bit (m<<2)|k : label 4*lane+256m+k locked

    // exact top-2 row scan of label L over unseen cols (tie -> larger col); lane63 holds result
    auto scan_row = [&](int L, u64 &r1, u64 &r2) {
        u64 a1 = 0, a2 = 0;
        if (JM) {
            const float4* row4 = (const float4*)(JM + (size_t)L * NBOX);
            #pragma unroll
            for (int m = 0; m < 4; ++m) {
                float4 f = row4[lane + 64 * m];
                float* ff = (float*)&f;
                #pragma unroll
                for (int k = 0; k < 4; ++k) {
                    int cc = 4 * lane + 256 * m + k;
                    u64 p = ((u64)__float_as_uint(ff[k]) << 10) | (unsigned)cc;
                    if ((myseen >> ((m << 2) | k)) & 1u) p = 0;
                    a2 = umax64(a2, umin64(a1, p));
                    a1 = umax64(a1, p);
                }
            }
        } else {
            float4 lb = lab4s[L];
            float la = larea_s[L];
            #pragma unroll
            for (int m = 0; m < 4; ++m) {
                #pragma unroll
                for (int k = 0; k < 4; ++k) {
                    int cc = 4 * lane + 256 * m + k;
                    float v = iou_pair(lb, la, pred4s[cc], parea_s[cc]);
                    u64 p = ((u64)__float_as_uint(v) << 10) | (unsigned)cc;
                    if ((myseen >> ((m << 2) | k)) & 1u) p = 0;
                    a2 = umax64(a2, umin64(a1, p));
                    a1 = umax64(a1, p);
                }
            }
        }
        dpp_top2(a1, a2);
        r1 = a1; r2 = a2;    // valid at lane 63
    };

    // exact col scan over unlocked labels (tie -> larger CURRENT pos); uniform result
    auto scan_col = [&](int c) -> u64 {
        u64 best = 0; u32 v1 = 0, v2 = 0;
        if (JMT) {
            const float4* col4 = (const float4*)(JMT + (size_t)c * NBOX);
            #pragma unroll
            for (int m = 0; m < 4; ++m) {
                float4 f = col4[lane + 64 * m];
                float* ff = (float*)&f;
                #pragma unroll
                for (int k = 0; k < 4; ++k) {
                    int L = 4 * lane + 256 * m + k;
                    u32 vb = __float_as_uint(ff[k]);
                    if ((mylocked >> ((m << 2) | k)) & 1u) vb = 0;
                    if (vb >= v1) { v2 = v1; v1 = vb; } else { v2 = (vb > v2) ? vb : v2; }
                    u64 key = ((u64)vb << 20) | ((u64)pos_s[L] << 10) | (unsigned)L;
                    if (!vb) key = 0;
                    best = umax64(best, key);
                }
            }
        } else {
            float4 pc = pred4s[c];
            float  pa = parea_s[c];
            #pragma unroll
            for (int m = 0; m < 4; ++m) {
                #pragma unroll
                for (int k = 0; k < 4; ++k) {
                    int L = 4 * lane + 256 * m + k;
                    float v = iou_pair(lab4s[L], larea_s[L], pc, pa);
                    u32 vb = __float_as_uint(v);
                    if ((mylocked >> ((m << 2) | k)) & 1u) vb = 0;
                    if (vb >= v1) { v2 = v1; v1 = vb; } else { v2 = (vb > v2) ? vb : v2; }
                    u64 key = ((u64)vb << 20) | ((u64)pos_s[L] << 10) | (unsigned)L;
                    if (!vb) key = 0;
                    best = umax64(best, key);
                }
            }
        }
        best = dpp_max64(best);
        u64 bm = readlane64(best, 63);
        u32 V = (u32)(bm >> 20);
        u64 b1 = __ballot(v1 == V);
        u64 b2 = __ballot(v2 == V);
        bool tie = (__popcll(b1) >= 2) || (b2 != 0ull);
        return V ? (((u64)V << 32) | (tie ? (1ull << 16) : 0ull) | (bm & 1023ull)) : 0ull;
    };

    if (!rkey_ws) {   // in-kernel init fallback
        for (int L = wid; L < NBOX; L += 16) {
            u64 r1, r2; scan_row(L, r1, r2);
            if (lane == 63) {
                if ((r1 >> 10) == 0ull) { rkey[L] = 0ull; rkey2[L] = 0ull; }
                else { rkey[L] = r1; rkey2[L] = (r2 >> 10) ? r2 : 0ull; }
            }
        }
        for (int c = wid; c < NBOX; c += 16) {
            u64 cbv = scan_col(c);
            if (lane == 0) cub[c] = cbv;
        }
        __syncthreads();
    }

    for (int round = 0; round < 2048; ++round) {
        // ---- B: row rescans (wave-cooperative, top-2 refill) ----
        {
            const int nq = nrowq;
            for (int i = wid; i < nq; i += 16) {
                int L = rowq[i];
                u64 r1, r2; scan_row(L, r1, r2);
                if (lane == 63) {
                    if ((r1 >> 10) == 0ull) { rkey[L] = 0ull; rkey2[L] = 0ull; }
                    else { rkey[L] = r1; rkey2[L] = (r2 >> 10) ? r2 : 0ull; }
                }
            }
        }
        __syncthreads();

        // ---- C: suitor push ----
        {
            u64 k = rkey[t];
            if (k) atomicMax((unsigned long long*)&colbest[k & 1023ull],
                             ((k >> 10) << 20) | ((u64)pos_s[t] << 10) | (u64)(unsigned)t);
        }
        __syncthreads();

        // ---- D: per-col fast check via cached bound ----
        {
            u64 sb = colbest[t];
            if (sb) {
                u32 sval = (u32)(sb >> 20);
                u32 slab = (u32)(sb & 1023ull);
                u64 cb = cub[t];
                u32 cval = (u32)(cb >> 32);
                u32 clab = (u32)(cb & 1023ull);
                bool ctie = (cb >> 16) & 1ull;
                if (lockedl[clab] || ctie || (sval == cval && slab != clab)) {
                    int ix = atomicAdd(&ncolq, 1); colq[ix] = (u16)t;
                } else if (slab == clab) {
                    int ix = atomicAdd(&ncommit, 1);
                    commits[ix] = ((u32)t << 16) | slab;
                }
            }
        }
        __syncthreads();

        // ---- E: col rescans, refresh bounds ----
        {
            const int nq = ncolq;
            for (int i = wid; i < nq; i += 16) {
                int c = colq[i];
                u64 cbv = scan_col(c);
                if (lane == 0) cub[c] = cbv;
            }
        }
        __syncthreads();

        // ---- F: re-check rescanned cols ----
        {
            const int nq = ncolq;
            for (int i = t; i < nq; i += 1024) {
                int c = colq[i];
                u64 sb = colbest[c];
                u64 cb = cub[c];
                if (sb && cb && (u32)(cb & 1023ull) == (u32)(sb & 1023ull)) {
                    int ix = atomicAdd(&ncommit, 1);
                    commits[ix] = ((u32)c << 16) | (u32)(sb & 1023ull);
                }
            }
        }
        __syncthreads();

        // ---- G: apply commits + register-mask updates + reset counters ----
        const int nc = ncommit;
        for (int i = t; i < nc; i += 1024) {
            u32 e = commits[i];
            int c = (int)(e >> 16), L = (int)(e & 0xFFFFu);
            seenc[c] = 1; lockedl[L] = 1; rkey[L] = 0ull;
            dest_s[L] = (u16)c; perm_s[c] = (u16)L;
        }
        for (int i = 0; i < nc; ++i) {           // all threads: maintain register masks
            u32 e = commits[i];
            int c = (int)(e >> 16), L = (int)(e & 0xFFFFu);
            if (((c >> 2) & 63) == lane) myseen   |= 1u << (((c >> 8) << 2) | (c & 3));
            if (((L >> 2) & 63) == lane) mylocked |= 1u << (((L >> 8) << 2) | (L & 3));
        }
        if (t == 0) { nrowq = 0; ncolq = 0; ncommit = 0; }
        __syncthreads();

        // ---- H: promotion / rowq build + clear suitors + compressed chase ----
        colbest[t] = 0ull;
        {
            u64 k = rkey[t];
            if (k && seenc[k & 1023ull]) {
                u64 k2 = rkey2[t];
                if (k2 != UNK) {
                    rkey[t] = k2;              // exact promotion (or dead if 0)
                    rkey2[t] = UNK;
                    if (k2 && seenc[k2 & 1023ull]) {
                        int ix = atomicAdd(&nrowq, 1); rowq[ix] = (u16)t;
                    }
                } else {
                    int ix = atomicAdd(&nrowq, 1); rowq[ix] = (u16)t;
                }
            }
        }
        if (!seenc[t]) {
            int l = (int)perm_s[t];              // resume from last endpoint
            while (lockedl[l]) l = (int)dest_s[l];
            pos_s[l] = (u16)t;
            perm_s[t] = (u16)l;
        }
        __syncthreads();

        if (nc == 0) break;
    }

    // ---- loss = mean |labels[perm] - predictions| ----
    {
        float4 lb = lab4s[perm_s[t]];
        float4 pb = pred4s[t];
        float sum = fabsf(lb.x - pb.x) + fabsf(lb.y - pb.y) +
                    fabsf(lb.z - pb.z) + fabsf(lb.w - pb.w);
        for (int off = 32; off > 0; off >>= 1) sum += __shfl_xor(sum, off, 64);
        if (lane == 0) fpart[wid] = sum;
        __syncthreads();
        if (t == 0) {
            float s = 0.0f;
            for (int w = 0; w < 16; ++w) s += fpart[w];
            out[0] = s * (1.0f / 4096.0f);
        }
    }
}

extern "C" void kernel_launch(void* const* d_in, const int* in_sizes, int n_in,
                              void* d_out, int out_size, void* d_ws, size_t ws_size,
                              hipStream_t stream) {
    const float* preds  = (const float*)d_in[0];   // predictions [1024,4]
    const float* labels = (const float*)d_in[1];   // labels      [1024,4]
    float* out = (float*)d_out;

    const size_t jm_b   = (size_t)NBOX * NBOX * sizeof(float);   // 4 MB
    const size_t keys_b = 3 * NBOX * sizeof(u64);                // 24 KB

    float *JM = nullptr, *JMT = nullptr;
    u64 *rk = nullptr, *rk2 = nullptr, *cb = nullptr;
    char* w = (char*)d_ws;

    if (d_ws && ws_size >= 2 * jm_b + keys_b) {
        JM  = (float*)w;
        JMT = (float*)(w + jm_b);
        rk  = (u64*)(w + 2 * jm_b); rk2 = rk + NBOX; cb = rk2 + NBOX;
    } else if (d_ws && ws_size >= jm_b + keys_b) {
        JM  = (float*)w;
        rk  = (u64*)(w + jm_b); rk2 = rk + NBOX; cb = rk2 + NBOX;
    } else if (d_ws && ws_size >= keys_b) {
        rk  = (u64*)w; rk2 = rk + NBOX; cb = rk2 + NBOX;
    }

    if (rk) {
        jm_init<<<NBOX, 64, 0, stream>>>(labels, preds, JM, JMT, rk, rk2);
        init_colmax<<<NBOX, 64, 0, stream>>>(labels, preds, cb);
    }
    rounds_kernel<<<1, 1024, 0, stream>>>(preds, labels, JM, JMT, rk, rk2, cb, out);
}

// Round 12
// 246.001 us; speedup vs baseline: 10.2180x; 1.3226x over previous
//
#include <hip/hip_runtime.h>
#include <stdint.h>

#define NBOX 1024
#define UNK  0xFFFFFFFFFFFFFFFFull

typedef unsigned long long u64;
typedef unsigned int u32;
typedef unsigned short u16;
typedef unsigned char u8;

// ---------- bit-exact IoU (matches numpy f32 op-for-op; _rn blocks FMA contraction) ----------
__device__ __forceinline__ float iou_pair(const float4 lb, float larea,
                                          const float4 pb, float parea) {
    float ix1 = fmaxf(lb.x, pb.x);
    float iy1 = fmaxf(lb.y, pb.y);
    float ix2 = fminf(lb.z, pb.z);
    float iy2 = fminf(lb.w, pb.w);
    float w = fmaxf(__fsub_rn(ix2, ix1), 0.0f);
    float h = fmaxf(__fsub_rn(iy2, iy1), 0.0f);
    float inter = __fmul_rn(w, h);
    float denom = __fsub_rn(__fadd_rn(larea, parea), inter);
    return inter / denom;
}

__device__ __forceinline__ u64 umax64(u64 a, u64 b) { return a > b ? a : b; }
__device__ __forceinline__ u64 umin64(u64 a, u64 b) { return a < b ? a : b; }

// ---------- 64-lane u64 max butterfly via DPP; result valid in lane 63 ----------
__device__ __forceinline__ u64 dpp_max64(u64 v) {
    unsigned lo, hi; u64 o;
#define DPP_STEP(CTRL) \
    lo = (unsigned)__builtin_amdgcn_update_dpp(0, (int)(unsigned)(v & 0xffffffffull), CTRL, 0xf, 0xf, true); \
    hi = (unsigned)__builtin_amdgcn_update_dpp(0, (int)(unsigned)(v >> 32),           CTRL, 0xf, 0xf, true); \
    o = (((u64)hi) << 32) | lo; \
    if (o > v) v = o;
    DPP_STEP(0x111) DPP_STEP(0x112) DPP_STEP(0x114)
    DPP_STEP(0x118) DPP_STEP(0x142) DPP_STEP(0x143)
#undef DPP_STEP
    return v;
}

// ---------- 64-lane top-2 reduce (distinct packed keys, disjoint prefix sets) ----------
__device__ __forceinline__ void dpp_top2(u64 &a1, u64 &a2) {
    unsigned lo, hi; u64 b1, b2, min1;
#define T2STEP(CTRL) \
    lo = (unsigned)__builtin_amdgcn_update_dpp(0, (int)(unsigned)(a1 & 0xffffffffull), CTRL, 0xf, 0xf, true); \
    hi = (unsigned)__builtin_amdgcn_update_dpp(0, (int)(unsigned)(a1 >> 32),           CTRL, 0xf, 0xf, true); \
    b1 = (((u64)hi) << 32) | lo; \
    lo = (unsigned)__builtin_amdgcn_update_dpp(0, (int)(unsigned)(a2 & 0xffffffffull), CTRL, 0xf, 0xf, true); \
    hi = (unsigned)__builtin_amdgcn_update_dpp(0, (int)(unsigned)(a2 >> 32),           CTRL, 0xf, 0xf, true); \
    b2 = (((u64)hi) << 32) | lo; \
    min1 = (b1 == a1) ? 0ull : umin64(a1, b1); \
    a1 = umax64(a1, b1); \
    a2 = umax64(umax64(a2, b2), min1);
    T2STEP(0x111) T2STEP(0x112) T2STEP(0x114) T2STEP(0x118) T2STEP(0x142) T2STEP(0x143)
#undef T2STEP
}

__device__ __forceinline__ u64 readlane64(u64 v, int l) {
    unsigned lo = (unsigned)__builtin_amdgcn_readlane((int)(unsigned)(v & 0xffffffffull), l);
    unsigned hi = (unsigned)__builtin_amdgcn_readlane((int)(unsigned)(v >> 32), l);
    return (((u64)hi) << 32) | lo;
}

// =====================================================================================
// Init A (1024 blocks): JM row b + top-2 row keys for label b.
// =====================================================================================
__global__ void __launch_bounds__(64) jm_init(const float* __restrict__ labels,
                                              const float* __restrict__ preds,
                                              float* __restrict__ JM,      // may be null
                                              u64* __restrict__ rkey_ws,
                                              u64* __restrict__ rkey2_ws) {
    const int b = blockIdx.x;
    const int lane = threadIdx.x;
    float4 lb = ((const float4*)labels)[b];
    float la = __fmul_rn(__fsub_rn(lb.z, lb.x), __fsub_rn(lb.w, lb.y));
    u64 a1 = 0, a2 = 0;
    #pragma unroll
    for (int m = 0; m < 4; ++m) {
        float4 v;
        float* vv = (float*)&v;
        #pragma unroll
        for (int k = 0; k < 4; ++k) {
            int c = 4 * lane + 256 * m + k;
            float4 pb = ((const float4*)preds)[c];
            float pa = __fmul_rn(__fsub_rn(pb.z, pb.x), __fsub_rn(pb.w, pb.y));
            vv[k] = iou_pair(lb, la, pb, pa);
        }
        if (JM) ((float4*)JM)[b * 256 + lane + 64 * m] = v;
        #pragma unroll
        for (int k = 0; k < 4; ++k) {
            int c = 4 * lane + 256 * m + k;
            u64 p = ((u64)__float_as_uint(vv[k]) << 10) | (unsigned)c;
            a2 = umax64(a2, umin64(a1, p));
            a1 = umax64(a1, p);
        }
    }
    dpp_top2(a1, a2);
    if (lane == 63) {
        if ((a1 >> 10) == 0ull) { rkey_ws[b] = 0ull; rkey2_ws[b] = 0ull; }
        else { rkey_ws[b] = a1; rkey2_ws[b] = (a2 >> 10) ? a2 : 0ull; }
    }
}

// =====================================================================================
// Init B (1024 blocks): col bound cub + coalesced JMT row (JMT[c][L] = IoU(L, c)).
// =====================================================================================
__global__ void __launch_bounds__(64) init_colmax(const float* __restrict__ labels,
                                                  const float* __restrict__ preds,
                                                  float* __restrict__ JMT,   // may be null
                                                  u64* __restrict__ cub_ws) {
    const int c = blockIdx.x;
    const int lane = threadIdx.x;
    float4 pc = ((const float4*)preds)[c];
    float pa = __fmul_rn(__fsub_rn(pc.z, pc.x), __fsub_rn(pc.w, pc.y));
    u64 best = 0; u32 v1 = 0, v2 = 0;
    #pragma unroll
    for (int j = 0; j < 16; ++j) {
        int L = lane + (j << 6);
        float4 lb = ((const float4*)labels)[L];
        float la = __fmul_rn(__fsub_rn(lb.z, lb.x), __fsub_rn(lb.w, lb.y));
        float v = iou_pair(lb, la, pc, pa);
        if (JMT) JMT[(size_t)c * NBOX + L] = v;
        u32 vb = __float_as_uint(v);
        if (vb >= v1) { v2 = v1; v1 = vb; } else { v2 = (vb > v2) ? vb : v2; }
        best = umax64(best, ((u64)vb << 10) | (unsigned)L);
    }
    best = dpp_max64(best);
    u64 bm = readlane64(best, 63);
    u32 V = (u32)(bm >> 10);
    u64 b1 = __ballot(v1 == V);
    u64 b2 = __ballot(v2 == V);
    bool tie = (__popcll(b1) >= 2) || (b2 != 0ull);
    if (lane == 63)
        cub_ws[c] = V ? (((u64)V << 32) | (tie ? (1ull << 16) : 0ull) | (bm & 1023ull))
                      : 0ull;
}

// =====================================================================================
// Main: 16-wave parallel greedy. 3 barriers/round: C(push) | DEF(check+scan+commit) |
//   H(mask rebuild + promote + row scans + chase). Immediate commit application.
// =====================================================================================
__global__ void __launch_bounds__(1024, 1)
rounds_kernel(const float* __restrict__ preds,
              const float* __restrict__ labels,
              const float* __restrict__ JM,      // may be null
              const float* __restrict__ JMT,     // may be null
              const u64* __restrict__ rkey_ws,   // may be null (then all ws null)
              const u64* __restrict__ rkey2_ws,
              const u64* __restrict__ cub_ws,
              float* __restrict__ out) {
    __shared__ float4 pred4s[NBOX];
    __shared__ float4 lab4s[NBOX];
    __shared__ float  parea_s[NBOX];
    __shared__ float  larea_s[NBOX];
    __shared__ u64    rkey[NBOX];
    __shared__ u64    rkey2[NBOX];
    __shared__ u64    cub[NBOX];
    __shared__ u64    colbest[NBOX];
    __shared__ u16    pos_s[NBOX];
    __shared__ u16    dest_s[NBOX];
    __shared__ u16    perm_s[NBOX];
    __shared__ u8     seenc[NBOX];
    __shared__ u8     lockedl[NBOX];
    __shared__ u32    seenw[32];
    __shared__ u32    lockedw[32];
    __shared__ int    ncommit;
    __shared__ float  fpart[16];

    const int t    = (int)threadIdx.x;
    const int lane = t & 63;
    const int wid  = t >> 6;

    {
        float4 p = ((const float4*)preds)[t];
        float4 L = ((const float4*)labels)[t];
        pred4s[t] = p;
        lab4s[t]  = L;
        parea_s[t] = __fmul_rn(__fsub_rn(p.z, p.x), __fsub_rn(p.w, p.y));
        larea_s[t] = __fmul_rn(__fsub_rn(L.z, L.x), __fsub_rn(L.w, L.y));
        pos_s[t] = (u16)t; perm_s[t] = (u16)t; dest_s[t] = 0;
        seenc[t] = 0; lockedl[t] = 0;
        rkey[t]  = rkey_ws  ? rkey_ws[t]  : 0ull;
        rkey2[t] = rkey2_ws ? rkey2_ws[t] : UNK;
        cub[t]   = cub_ws   ? cub_ws[t]   : 0ull;
        colbest[t] = 0ull;
        if (t < 32) { seenw[t] = 0u; lockedw[t] = 0u; }
        if (t == 0) ncommit = 0;
    }
    __syncthreads();

    u32 myseen = 0;    // bit (m<<2)|k : col 4*lane+256m+k consumed
    u32 mylocked = 0;  // bit (m<<2)|k : label 4*lane+256m+k locked

    // exact top-2 row scan of label L over unseen cols (tie -> larger col); lane63 holds result
    auto scan_row = [&](int L, u64 &r1, u64 &r2) {
        u64 a1 = 0, a2 = 0;
        if (JM) {
            const float4* row4 = (const float4*)(JM + (size_t)L * NBOX);
            #pragma unroll
            for (int m = 0; m < 4; ++m) {
                float4 f = row4[lane + 64 * m];
                float* ff = (float*)&f;
                #pragma unroll
                for (int k = 0; k < 4; ++k) {
                    int cc = 4 * lane + 256 * m + k;
                    u64 p = ((u64)__float_as_uint(ff[k]) << 10) | (unsigned)cc;
                    if ((myseen >> ((m << 2) | k)) & 1u) p = 0;
                    a2 = umax64(a2, umin64(a1, p));
                    a1 = umax64(a1, p);
                }
            }
        } else {
            float4 lb = lab4s[L];
            float la = larea_s[L];
            #pragma unroll
            for (int m = 0; m < 4; ++m) {
                #pragma unroll
                for (int k = 0; k < 4; ++k) {
                    int cc = 4 * lane + 256 * m + k;
                    float v = iou_pair(lb, la, pred4s[cc], parea_s[cc]);
                    u64 p = ((u64)__float_as_uint(v) << 10) | (unsigned)cc;
                    if ((myseen >> ((m << 2) | k)) & 1u) p = 0;
                    a2 = umax64(a2, umin64(a1, p));
                    a1 = umax64(a1, p);
                }
            }
        }
        dpp_top2(a1, a2);
        r1 = a1; r2 = a2;
    };

    // exact col scan over unlocked labels (tie -> larger CURRENT pos); uniform result
    auto scan_col = [&](int c) -> u64 {
        u64 best = 0; u32 v1 = 0, v2 = 0;
        if (JMT) {
            const float4* col4 = (const float4*)(JMT + (size_t)c * NBOX);
            #pragma unroll
            for (int m = 0; m < 4; ++m) {
                float4 f = col4[lane + 64 * m];
                float* ff = (float*)&f;
                #pragma unroll
                for (int k = 0; k < 4; ++k) {
                    int L = 4 * lane + 256 * m + k;
                    u32 vb = __float_as_uint(ff[k]);
                    if ((mylocked >> ((m << 2) | k)) & 1u) vb = 0;
                    if (vb >= v1) { v2 = v1; v1 = vb; } else { v2 = (vb > v2) ? vb : v2; }
                    u64 key = ((u64)vb << 20) | ((u64)pos_s[L] << 10) | (unsigned)L;
                    if (!vb) key = 0;
                    best = umax64(best, key);
                }
            }
        } else {
            float4 pc = pred4s[c];
            float  pa = parea_s[c];
            #pragma unroll
            for (int m = 0; m < 4; ++m) {
                #pragma unroll
                for (int k = 0; k < 4; ++k) {
                    int L = 4 * lane + 256 * m + k;
                    float v = iou_pair(lab4s[L], larea_s[L], pc, pa);
                    u32 vb = __float_as_uint(v);
                    if ((mylocked >> ((m << 2) | k)) & 1u) vb = 0;
                    if (vb >= v1) { v2 = v1; v1 = vb; } else { v2 = (vb > v2) ? vb : v2; }
                    u64 key = ((u64)vb << 20) | ((u64)pos_s[L] << 10) | (unsigned)L;
                    if (!vb) key = 0;
                    best = umax64(best, key);
                }
            }
        }
        best = dpp_max64(best);
        u64 bm = readlane64(best, 63);
        u32 V = (u32)(bm >> 20);
        u64 b1 = __ballot(v1 == V);
        u64 b2 = __ballot(v2 == V);
        bool tie = (__popcll(b1) >= 2) || (b2 != 0ull);
        return V ? (((u64)V << 32) | (tie ? (1ull << 16) : 0ull) | (bm & 1023ull)) : 0ull;
    };

    if (!rkey_ws) {   // in-kernel init fallback
        for (int L = wid; L < NBOX; L += 16) {
            u64 r1, r2; scan_row(L, r1, r2);
            if (lane == 63) {
                if ((r1 >> 10) == 0ull) { rkey[L] = 0ull; rkey2[L] = 0ull; }
                else { rkey[L] = r1; rkey2[L] = (r2 >> 10) ? r2 : 0ull; }
            }
        }
        for (int c = wid; c < NBOX; c += 16) {
            u64 cbv = scan_col(c);
            if (lane == 0) cub[c] = cbv;
        }
        __syncthreads();
    }

    for (int round = 0; round < 2048; ++round) {
        // ---- C: suitor push (+ counter reset) ----
        {
            u64 k = rkey[t];
            if (k) atomicMax((unsigned long long*)&colbest[k & 1023ull],
                             ((k >> 10) << 20) | ((u64)pos_s[t] << 10) | (u64)(unsigned)t);
            if (t == 0) ncommit = 0;
        }
        __syncthreads();

        // ---- DEF: fast check -> ballot-driven col scans -> immediate commit apply ----
        {
            bool need = false;
            u64 sb = colbest[t];
            if (sb) {
                u32 sval = (u32)(sb >> 20);
                u32 slab = (u32)(sb & 1023ull);
                u64 cb = cub[t];
                u32 cval = (u32)(cb >> 32);
                u32 clab = (u32)(cb & 1023ull);
                bool ctie = (cb >> 16) & 1ull;
                if (lockedl[clab] || ctie || (sval == cval && slab != clab)) {
                    need = true;
                } else if (slab == clab) {        // dominant pair: commit now
                    int c = t, L = (int)slab;
                    seenc[c] = 1; lockedl[L] = 1; rkey[L] = 0ull;
                    dest_s[L] = (u16)c; perm_s[c] = (u16)L;
                    atomicOr(&seenw[c >> 5], 1u << (c & 31));
                    atomicOr(&lockedw[L >> 5], 1u << (L & 31));
                    atomicAdd(&ncommit, 1);
                }
            }
            u64 bal = __ballot(need);
            while (bal) {
                int l = (int)__ffsll(bal) - 1;
                bal &= bal - 1;
                int c = (wid << 6) | l;
                u64 cbv = scan_col(c);
                if (lane == 0) {
                    cub[c] = cbv;
                    u64 sb2 = colbest[c];
                    if (sb2 && cbv && (u32)(cbv & 1023ull) == (u32)(sb2 & 1023ull)) {
                        int L = (int)(sb2 & 1023ull);
                        seenc[c] = 1; lockedl[L] = 1; rkey[L] = 0ull;
                        dest_s[L] = (u16)c; perm_s[c] = (u16)L;
                        atomicOr(&seenw[c >> 5], 1u << (c & 31));
                        atomicOr(&lockedw[L >> 5], 1u << (L & 31));
                        atomicAdd(&ncommit, 1);
                    }
                }
            }
        }
        __syncthreads();

        // ---- H: rebuild masks, promote rows (+inline scans), chase, clear suitors ----
        const int nc = ncommit;
        {
            u32 ms = 0, ml = 0;
            #pragma unroll
            for (int m = 0; m < 4; ++m) {
                u32 ws_ = seenw[(lane >> 3) + (m << 3)];
                u32 wl  = lockedw[(lane >> 3) + (m << 3)];
                u32 sh  = (lane & 7) << 2;
                ms |= ((ws_ >> sh) & 0xFu) << (m << 2);
                ml |= ((wl  >> sh) & 0xFu) << (m << 2);
            }
            myseen = ms; mylocked = ml;
        }
        {
            bool needrow = false;
            u64 k = rkey[t];
            if (k && seenc[k & 1023ull]) {
                u64 k2 = rkey2[t];
                if (k2 != UNK) {
                    rkey[t] = k2;                 // exact promotion (or dead if 0)
                    rkey2[t] = UNK;
                    if (k2 && seenc[k2 & 1023ull]) needrow = true;
                } else {
                    needrow = true;
                }
            }
            u64 bal = __ballot(needrow);
            while (bal) {
                int l = (int)__ffsll(bal) - 1;
                bal &= bal - 1;
                int row = (wid << 6) | l;
                u64 r1, r2; scan_row(row, r1, r2);
                if (lane == 63) {
                    if ((r1 >> 10) == 0ull) { rkey[row] = 0ull; rkey2[row] = 0ull; }
                    else { rkey[row] = r1; rkey2[row] = (r2 >> 10) ? r2 : 0ull; }
                }
            }
        }
        colbest[t] = 0ull;
        if (!seenc[t]) {
            int l = (int)perm_s[t];               // resume from last endpoint
            while (lockedl[l]) l = (int)dest_s[l];
            pos_s[l] = (u16)t;
            perm_s[t] = (u16)l;
        }
        __syncthreads();

        if (nc == 0) break;                       // no live positive keys -> perm final
    }

    // ---- loss = mean |labels[perm] - predictions| ----
    {
        float4 lb = lab4s[perm_s[t]];
        float4 pb = pred4s[t];
        float sum = fabsf(lb.x - pb.x) + fabsf(lb.y - pb.y) +
                    fabsf(lb.z - pb.z) + fabsf(lb.w - pb.w);
        for (int off = 32; off > 0; off >>= 1) sum += __shfl_xor(sum, off, 64);
        if (lane == 0) fpart[wid] = sum;
        __syncthreads();
        if (t == 0) {
            float s = 0.0f;
            for (int w = 0; w < 16; ++w) s += fpart[w];
            out[0] = s * (1.0f / 4096.0f);
        }
    }
}

extern "C" void kernel_launch(void* const* d_in, const int* in_sizes, int n_in,
                              void* d_out, int out_size, void* d_ws, size_t ws_size,
                              hipStream_t stream) {
    const float* preds  = (const float*)d_in[0];   // predictions [1024,4]
    const float* labels = (const float*)d_in[1];   // labels      [1024,4]
    float* out = (float*)d_out;

    const size_t jm_b   = (size_t)NBOX * NBOX * sizeof(float);   // 4 MB
    const size_t keys_b = 3 * NBOX * sizeof(u64);                // 24 KB

    float *JM = nullptr, *JMT = nullptr;
    u64 *rk = nullptr, *rk2 = nullptr, *cb = nullptr;
    char* w = (char*)d_ws;

    if (d_ws && ws_size >= 2 * jm_b + keys_b) {
        JM  = (float*)w;
        JMT = (float*)(w + jm_b);
        rk  = (u64*)(w + 2 * jm_b); rk2 = rk + NBOX; cb = rk2 + NBOX;
    } else if (d_ws && ws_size >= jm_b + keys_b) {
        JM  = (float*)w;
        rk  = (u64*)(w + jm_b); rk2 = rk + NBOX; cb = rk2 + NBOX;
    } else if (d_ws && ws_size >= keys_b) {
        rk  = (u64*)w; rk2 = rk + NBOX; cb = rk2 + NBOX;
    }

    if (rk) {
        jm_init<<<NBOX, 64, 0, stream>>>(labels, preds, JM, rk, rk2);
        init_colmax<<<NBOX, 64, 0, stream>>>(labels, preds, JMT, cb);
    }
    rounds_kernel<<<1, 1024, 0, stream>>>(preds, labels, JM, JMT, rk, rk2, cb, out);
}

// Round 13
// 229.495 us; speedup vs baseline: 10.9529x; 1.0719x over previous
//
#include <hip/hip_runtime.h>
#include <stdint.h>

#define NBOX 1024
#define UNK  0xFFFFFFFFFFFFFFFFull

typedef unsigned long long u64;
typedef unsigned int u32;
typedef unsigned short u16;
typedef unsigned char u8;

// ---------- bit-exact IoU (matches numpy f32 op-for-op; _rn blocks FMA contraction) ----------
__device__ __forceinline__ float iou_pair(const float4 lb, float larea,
                                          const float4 pb, float parea) {
    float ix1 = fmaxf(lb.x, pb.x);
    float iy1 = fmaxf(lb.y, pb.y);
    float ix2 = fminf(lb.z, pb.z);
    float iy2 = fminf(lb.w, pb.w);
    float w = fmaxf(__fsub_rn(ix2, ix1), 0.0f);
    float h = fmaxf(__fsub_rn(iy2, iy1), 0.0f);
    float inter = __fmul_rn(w, h);
    float denom = __fsub_rn(__fadd_rn(larea, parea), inter);
    return inter / denom;
}

__device__ __forceinline__ u64 umax64(u64 a, u64 b) { return a > b ? a : b; }
__device__ __forceinline__ u64 umin64(u64 a, u64 b) { return a < b ? a : b; }

// ---------- 64-lane u64 max butterfly via DPP; result valid in lane 63 ----------
__device__ __forceinline__ u64 dpp_max64(u64 v) {
    unsigned lo, hi; u64 o;
#define DPP_STEP(CTRL) \
    lo = (unsigned)__builtin_amdgcn_update_dpp(0, (int)(unsigned)(v & 0xffffffffull), CTRL, 0xf, 0xf, true); \
    hi = (unsigned)__builtin_amdgcn_update_dpp(0, (int)(unsigned)(v >> 32),           CTRL, 0xf, 0xf, true); \
    o = (((u64)hi) << 32) | lo; \
    if (o > v) v = o;
    DPP_STEP(0x111) DPP_STEP(0x112) DPP_STEP(0x114)
    DPP_STEP(0x118) DPP_STEP(0x142) DPP_STEP(0x143)
#undef DPP_STEP
    return v;
}

// ---------- 64-lane top-2 reduce (distinct packed keys); result valid in lane 63 ----------
__device__ __forceinline__ void dpp_top2(u64 &a1, u64 &a2) {
    unsigned lo, hi; u64 b1, b2, min1;
#define T2STEP(CTRL) \
    lo = (unsigned)__builtin_amdgcn_update_dpp(0, (int)(unsigned)(a1 & 0xffffffffull), CTRL, 0xf, 0xf, true); \
    hi = (unsigned)__builtin_amdgcn_update_dpp(0, (int)(unsigned)(a1 >> 32),           CTRL, 0xf, 0xf, true); \
    b1 = (((u64)hi) << 32) | lo; \
    lo = (unsigned)__builtin_amdgcn_update_dpp(0, (int)(unsigned)(a2 & 0xffffffffull), CTRL, 0xf, 0xf, true); \
    hi = (unsigned)__builtin_amdgcn_update_dpp(0, (int)(unsigned)(a2 >> 32),           CTRL, 0xf, 0xf, true); \
    b2 = (((u64)hi) << 32) | lo; \
    min1 = (b1 == a1) ? 0ull : umin64(a1, b1); \
    a1 = umax64(a1, b1); \
    a2 = umax64(umax64(a2, b2), min1);
    T2STEP(0x111) T2STEP(0x112) T2STEP(0x114) T2STEP(0x118) T2STEP(0x142) T2STEP(0x143)
#undef T2STEP
}

__device__ __forceinline__ u64 readlane64(u64 v, int l) {
    unsigned lo = (unsigned)__builtin_amdgcn_readlane((int)(unsigned)(v & 0xffffffffull), l);
    unsigned hi = (unsigned)__builtin_amdgcn_readlane((int)(unsigned)(v >> 32), l);
    return (((u64)hi) << 32) | lo;
}
__device__ __forceinline__ u32 readlane32(u32 v, int l) {
    return (u32)__builtin_amdgcn_readlane((int)v, l);
}

// overlap-free 16-lane-row shift step for u64 top-2 (distinct keys, no dedupe needed)
#define SHR_T2_STEP(a1, a2, CTRL) { \
    unsigned _lo, _hi; u64 _b1, _b2, _mn; \
    _lo = (unsigned)__builtin_amdgcn_update_dpp(0, (int)(unsigned)((a1) & 0xffffffffull), CTRL, 0xf, 0xf, true); \
    _hi = (unsigned)__builtin_amdgcn_update_dpp(0, (int)(unsigned)((a1) >> 32),           CTRL, 0xf, 0xf, true); \
    _b1 = (((u64)_hi) << 32) | _lo; \
    _lo = (unsigned)__builtin_amdgcn_update_dpp(0, (int)(unsigned)((a2) & 0xffffffffull), CTRL, 0xf, 0xf, true); \
    _hi = (unsigned)__builtin_amdgcn_update_dpp(0, (int)(unsigned)((a2) >> 32),           CTRL, 0xf, 0xf, true); \
    _b2 = (((u64)_hi) << 32) | _lo; \
    _mn = umin64((a1), _b1); \
    (a1) = umax64((a1), _b1); \
    (a2) = umax64(umax64((a2), _b2), _mn); }

// overlap-free 16-lane-row shift step for u32 (v1,v2); equal values correctly flag v2==v1
#define SHR_V2_STEP(v1, v2, CTRL) { \
    u32 _s1 = (u32)__builtin_amdgcn_update_dpp(0, (int)(v1), CTRL, 0xf, 0xf, true); \
    u32 _s2 = (u32)__builtin_amdgcn_update_dpp(0, (int)(v2), CTRL, 0xf, 0xf, true); \
    u32 _mn = (v1) < _s1 ? (v1) : _s1; \
    (v1) = (v1) > _s1 ? (v1) : _s1; \
    u32 _m2 = (v2) > _s2 ? (v2) : _s2; \
    (v2) = _m2 > _mn ? _m2 : _mn; }

// =====================================================================================
// Init A (1024 blocks): JM row b + top-2 row keys for label b.
// =====================================================================================
__global__ void __launch_bounds__(64) jm_init(const float* __restrict__ labels,
                                              const float* __restrict__ preds,
                                              float* __restrict__ JM,      // may be null
                                              u64* __restrict__ rkey_ws,
                                              u64* __restrict__ rkey2_ws) {
    const int b = blockIdx.x;
    const int lane = threadIdx.x;
    float4 lb = ((const float4*)labels)[b];
    float la = __fmul_rn(__fsub_rn(lb.z, lb.x), __fsub_rn(lb.w, lb.y));
    u64 a1 = 0, a2 = 0;
    #pragma unroll
    for (int m = 0; m < 4; ++m) {
        float4 v;
        float* vv = (float*)&v;
        #pragma unroll
        for (int k = 0; k < 4; ++k) {
            int c = 4 * lane + 256 * m + k;
            float4 pb = ((const float4*)preds)[c];
            float pa = __fmul_rn(__fsub_rn(pb.z, pb.x), __fsub_rn(pb.w, pb.y));
            vv[k] = iou_pair(lb, la, pb, pa);
        }
        if (JM) ((float4*)JM)[b * 256 + lane + 64 * m] = v;
        #pragma unroll
        for (int k = 0; k < 4; ++k) {
            int c = 4 * lane + 256 * m + k;
            u64 p = ((u64)__float_as_uint(vv[k]) << 10) | (unsigned)c;
            a2 = umax64(a2, umin64(a1, p));
            a1 = umax64(a1, p);
        }
    }
    dpp_top2(a1, a2);
    if (lane == 63) {
        if ((a1 >> 10) == 0ull) { rkey_ws[b] = 0ull; rkey2_ws[b] = 0ull; }
        else { rkey_ws[b] = a1; rkey2_ws[b] = (a2 >> 10) ? a2 : 0ull; }
    }
}

// =====================================================================================
// Init B (1024 blocks): col bound cub + coalesced JMT row (JMT[c][L] = IoU(L, c)).
// =====================================================================================
__global__ void __launch_bounds__(64) init_colmax(const float* __restrict__ labels,
                                                  const float* __restrict__ preds,
                                                  float* __restrict__ JMT,   // may be null
                                                  u64* __restrict__ cub_ws) {
    const int c = blockIdx.x;
    const int lane = threadIdx.x;
    float4 pc = ((const float4*)preds)[c];
    float pa = __fmul_rn(__fsub_rn(pc.z, pc.x), __fsub_rn(pc.w, pc.y));
    u64 best = 0; u32 v1 = 0, v2 = 0;
    #pragma unroll
    for (int j = 0; j < 16; ++j) {
        int L = lane + (j << 6);
        float4 lb = ((const float4*)labels)[L];
        float la = __fmul_rn(__fsub_rn(lb.z, lb.x), __fsub_rn(lb.w, lb.y));
        float v = iou_pair(lb, la, pc, pa);
        if (JMT) JMT[(size_t)c * NBOX + L] = v;
        u32 vb = __float_as_uint(v);
        if (vb >= v1) { v2 = v1; v1 = vb; } else { v2 = (vb > v2) ? vb : v2; }
        best = umax64(best, ((u64)vb << 10) | (unsigned)L);
    }
    best = dpp_max64(best);
    u64 bm = readlane64(best, 63);
    u32 V = (u32)(bm >> 10);
    u64 b1 = __ballot(v1 == V);
    u64 b2 = __ballot(v2 == V);
    bool tie = (__popcll(b1) >= 2) || (b2 != 0ull);
    if (lane == 63)
        cub_ws[c] = V ? (((u64)V << 32) | (tie ? (1ull << 16) : 0ull) | (bm & 1023ull))
                      : 0ull;
}

// =====================================================================================
// Main: 16-wave parallel greedy; pairwise-interleaved scans, 32-bit in-lane tracking,
//   overlap-free 4-step shift reduce + scalar merge. Commit semantics identical to R12.
// =====================================================================================
__global__ void __launch_bounds__(1024, 1)
rounds_kernel(const float* __restrict__ preds,
              const float* __restrict__ labels,
              const float* __restrict__ JM,      // may be null
              const float* __restrict__ JMT,     // may be null
              const u64* __restrict__ rkey_ws,   // may be null (then all ws null)
              const u64* __restrict__ rkey2_ws,
              const u64* __restrict__ cub_ws,
              float* __restrict__ out) {
    __shared__ float4 pred4s[NBOX];
    __shared__ float4 lab4s[NBOX];
    __shared__ float  parea_s[NBOX];
    __shared__ float  larea_s[NBOX];
    __shared__ u64    rkey[NBOX];
    __shared__ u64    rkey2[NBOX];
    __shared__ u64    cub[NBOX];
    __shared__ u64    colbest[NBOX];
    __shared__ u16    pos_s[NBOX];
    __shared__ u16    dest_s[NBOX];
    __shared__ u16    perm_s[NBOX];
    __shared__ u8     seenc[NBOX];
    __shared__ u8     lockedl[NBOX];
    __shared__ u32    seenw[32];
    __shared__ u32    lockedw[32];
    __shared__ int    ncommit;
    __shared__ float  fpart[16];

    const int t    = (int)threadIdx.x;
    const int lane = t & 63;
    const int wid  = t >> 6;

    {
        float4 p = ((const float4*)preds)[t];
        float4 L = ((const float4*)labels)[t];
        pred4s[t] = p;
        lab4s[t]  = L;
        parea_s[t] = __fmul_rn(__fsub_rn(p.z, p.x), __fsub_rn(p.w, p.y));
        larea_s[t] = __fmul_rn(__fsub_rn(L.z, L.x), __fsub_rn(L.w, L.y));
        pos_s[t] = (u16)t; perm_s[t] = (u16)t; dest_s[t] = 0;
        seenc[t] = 0; lockedl[t] = 0;
        rkey[t]  = rkey_ws  ? rkey_ws[t]  : 0ull;
        rkey2[t] = rkey2_ws ? rkey2_ws[t] : UNK;
        cub[t]   = cub_ws   ? cub_ws[t]   : 0ull;
        colbest[t] = 0ull;
        if (t < 32) { seenw[t] = 0u; lockedw[t] = 0u; }
        if (t == 0) ncommit = 0;
    }
    __syncthreads();

    u32 myseen = 0;    // bit (m<<2)|k : col 4*lane+256m+k consumed
    u32 mylocked = 0;  // bit (m<<2)|k : label 4*lane+256m+k locked

    // ---- pairwise exact top-2 row scan; uniform results (val<<10)|col packed ----
    auto scan_row2 = [&](int La, int Lb, bool hb,
                         u64 &r1a, u64 &r2a, u64 &r1b, u64 &r2b) {
        u32 av1 = 0, ac1 = 0, av2 = 0, ac2 = 0;
        u32 bv1 = 0, bc1 = 0, bv2 = 0, bc2 = 0;
        if (JM) {
            const float4* A4 = (const float4*)(JM + (size_t)La * NBOX);
            const float4* B4 = (const float4*)(JM + (size_t)Lb * NBOX);
            #pragma unroll
            for (int m = 0; m < 4; ++m) {
                float4 fa = A4[lane + 64 * m];
                float4 fb = B4[lane + 64 * m];
                const float* qa = (const float*)&fa;
                const float* qb = (const float*)&fb;
                #pragma unroll
                for (int k = 0; k < 4; ++k) {
                    u32 cc = (u32)(4 * lane + 256 * m + k);
                    bool msk = (myseen >> ((m << 2) | k)) & 1u;
                    u32 va = __float_as_uint(qa[k]);
                    u32 vb = __float_as_uint(qb[k]);
                    if (!msk && va) {
                        if (va >= av1) { av2 = av1; ac2 = ac1; av1 = va; ac1 = cc; }
                        else if (va >= av2) { av2 = va; ac2 = cc; }
                    }
                    if (!msk && vb) {
                        if (vb >= bv1) { bv2 = bv1; bc2 = bc1; bv1 = vb; bc1 = cc; }
                        else if (vb >= bv2) { bv2 = vb; bc2 = cc; }
                    }
                }
            }
        } else {
            float4 lba = lab4s[La]; float laa = larea_s[La];
            float4 lbb = lab4s[Lb]; float lbb_a = larea_s[Lb];
            #pragma unroll
            for (int m = 0; m < 4; ++m) {
                #pragma unroll
                for (int k = 0; k < 4; ++k) {
                    u32 cc = (u32)(4 * lane + 256 * m + k);
                    bool msk = (myseen >> ((m << 2) | k)) & 1u;
                    u32 va = __float_as_uint(iou_pair(lba, laa, pred4s[cc], parea_s[cc]));
                    u32 vb = __float_as_uint(iou_pair(lbb, lbb_a, pred4s[cc], parea_s[cc]));
                    if (!msk && va) {
                        if (va >= av1) { av2 = av1; ac2 = ac1; av1 = va; ac1 = cc; }
                        else if (va >= av2) { av2 = va; ac2 = cc; }
                    }
                    if (!msk && vb) {
                        if (vb >= bv1) { bv2 = bv1; bc2 = bc1; bv1 = vb; bc1 = cc; }
                        else if (vb >= bv2) { bv2 = vb; bc2 = cc; }
                    }
                }
            }
        }
        u64 a1 = ((u64)av1 << 10) | ac1, a2 = ((u64)av2 << 10) | ac2;
        u64 b1 = ((u64)bv1 << 10) | bc1, b2 = ((u64)bv2 << 10) | bc2;
        SHR_T2_STEP(a1, a2, 0x111) SHR_T2_STEP(b1, b2, 0x111)
        SHR_T2_STEP(a1, a2, 0x112) SHR_T2_STEP(b1, b2, 0x112)
        SHR_T2_STEP(a1, a2, 0x114) SHR_T2_STEP(b1, b2, 0x114)
        SHR_T2_STEP(a1, a2, 0x118) SHR_T2_STEP(b1, b2, 0x118)
        {
            u64 p1 = readlane64(a1, 15), p2 = readlane64(a2, 15);
            u64 q1 = readlane64(a1, 31), q2 = readlane64(a2, 31);
            u64 s1 = readlane64(a1, 47), s2 = readlane64(a2, 47);
            u64 w1 = readlane64(a1, 63), w2 = readlane64(a2, 63);
            u64 mn = umin64(p1, q1); p1 = umax64(p1, q1); p2 = umax64(umax64(p2, q2), mn);
            mn = umin64(s1, w1); s1 = umax64(s1, w1); s2 = umax64(umax64(s2, w2), mn);
            mn = umin64(p1, s1); p1 = umax64(p1, s1); p2 = umax64(umax64(p2, s2), mn);
            r1a = p1; r2a = p2;
        }
        if (hb) {
            u64 p1 = readlane64(b1, 15), p2 = readlane64(b2, 15);
            u64 q1 = readlane64(b1, 31), q2 = readlane64(b2, 31);
            u64 s1 = readlane64(b1, 47), s2 = readlane64(b2, 47);
            u64 w1 = readlane64(b1, 63), w2 = readlane64(b2, 63);
            u64 mn = umin64(p1, q1); p1 = umax64(p1, q1); p2 = umax64(umax64(p2, q2), mn);
            mn = umin64(s1, w1); s1 = umax64(s1, w1); s2 = umax64(umax64(s2, w2), mn);
            mn = umin64(p1, s1); p1 = umax64(p1, s1); p2 = umax64(umax64(p2, s2), mn);
            r1b = p1; r2b = p2;
        } else { r1b = 0; r2b = 0; }
    };

    // store top-2 row scan result (uniform in); lane 0 writes
    auto store_rkey = [&](int L, u64 r1, u64 r2) {
        if (lane == 0) {
            if ((r1 >> 10) == 0ull) { rkey[L] = 0ull; rkey2[L] = 0ull; }
            else { rkey[L] = r1; rkey2[L] = (r2 >> 10) ? r2 : 0ull; }
        }
    };

    // exact pos-aware col scan (slow path, ties only); uniform result
    auto scan_col_exact = [&](int c) -> u64 {
        u64 best = 0; u32 v1 = 0, v2 = 0;
        if (JMT) {
            const float4* col4 = (const float4*)(JMT + (size_t)c * NBOX);
            #pragma unroll
            for (int m = 0; m < 4; ++m) {
                float4 f = col4[lane + 64 * m];
                const float* ff = (const float*)&f;
                #pragma unroll
                for (int k = 0; k < 4; ++k) {
                    int L = 4 * lane + 256 * m + k;
                    u32 vb = __float_as_uint(ff[k]);
                    if ((mylocked >> ((m << 2) | k)) & 1u) vb = 0;
                    if (vb >= v1) { v2 = v1; v1 = vb; } else { v2 = (vb > v2) ? vb : v2; }
                    u64 key = ((u64)vb << 20) | ((u64)pos_s[L] << 10) | (unsigned)L;
                    if (!vb) key = 0;
                    best = umax64(best, key);
                }
            }
        } else {
            float4 pc = pred4s[c];
            float  pa = parea_s[c];
            #pragma unroll
            for (int m = 0; m < 4; ++m) {
                #pragma unroll
                for (int k = 0; k < 4; ++k) {
                    int L = 4 * lane + 256 * m + k;
                    float v = iou_pair(lab4s[L], larea_s[L], pc, pa);
                    u32 vb = __float_as_uint(v);
                    if ((mylocked >> ((m << 2) | k)) & 1u) vb = 0;
                    if (vb >= v1) { v2 = v1; v1 = vb; } else { v2 = (vb > v2) ? vb : v2; }
                    u64 key = ((u64)vb << 20) | ((u64)pos_s[L] << 10) | (unsigned)L;
                    if (!vb) key = 0;
                    best = umax64(best, key);
                }
            }
        }
        best = dpp_max64(best);
        u64 bm = readlane64(best, 63);
        u32 V = (u32)(bm >> 20);
        u64 b1 = __ballot(v1 == V);
        u64 b2 = __ballot(v2 == V);
        bool tie = (__popcll(b1) >= 2) || (b2 != 0ull);
        return V ? (((u64)V << 32) | (tie ? (1ull << 16) : 0ull) | (bm & 1023ull)) : 0ull;
    };

    // pairwise fast col scan; returns cub-format or UNK (tie -> caller runs exact)
    auto scan_col2 = [&](int ca, int cb, bool hb, u64 &oa, u64 &ob) {
        u32 av1 = 0, av2 = 0, al1 = 0;
        u32 bv1 = 0, bv2 = 0, bl1 = 0;
        if (JMT) {
            const float4* A4 = (const float4*)(JMT + (size_t)ca * NBOX);
            const float4* B4 = (const float4*)(JMT + (size_t)cb * NBOX);
            #pragma unroll
            for (int m = 0; m < 4; ++m) {
                float4 fa = A4[lane + 64 * m];
                float4 fb = B4[lane + 64 * m];
                const float* qa = (const float*)&fa;
                const float* qb = (const float*)&fb;
                #pragma unroll
                for (int k = 0; k < 4; ++k) {
                    u32 L = (u32)(4 * lane + 256 * m + k);
                    bool msk = (mylocked >> ((m << 2) | k)) & 1u;
                    u32 va = msk ? 0u : __float_as_uint(qa[k]);
                    u32 vb = msk ? 0u : __float_as_uint(qb[k]);
                    if (va > av1) { av2 = av1; av1 = va; al1 = L; }
                    else av2 = (va > av2) ? va : av2;
                    if (vb > bv1) { bv2 = bv1; bv1 = vb; bl1 = L; }
                    else bv2 = (vb > bv2) ? vb : bv2;
                }
            }
        } else {
            float4 pca = pred4s[ca]; float paa = parea_s[ca];
            float4 pcb = pred4s[cb]; float pab = parea_s[cb];
            #pragma unroll
            for (int m = 0; m < 4; ++m) {
                #pragma unroll
                for (int k = 0; k < 4; ++k) {
                    u32 L = (u32)(4 * lane + 256 * m + k);
                    bool msk = (mylocked >> ((m << 2) | k)) & 1u;
                    u32 va = msk ? 0u : __float_as_uint(iou_pair(lab4s[L], larea_s[L], pca, paa));
                    u32 vb = msk ? 0u : __float_as_uint(iou_pair(lab4s[L], larea_s[L], pcb, pab));
                    if (va > av1) { av2 = av1; av1 = va; al1 = L; }
                    else av2 = (va > av2) ? va : av2;
                    if (vb > bv1) { bv2 = bv1; bv1 = vb; bl1 = L; }
                    else bv2 = (vb > bv2) ? vb : bv2;
                }
            }
        }
        u32 sva = av1, sla = al1;      // pre-merge lane copies
        u32 svb = bv1, slb = bl1;
        SHR_V2_STEP(av1, av2, 0x111) SHR_V2_STEP(bv1, bv2, 0x111)
        SHR_V2_STEP(av1, av2, 0x112) SHR_V2_STEP(bv1, bv2, 0x112)
        SHR_V2_STEP(av1, av2, 0x114) SHR_V2_STEP(bv1, bv2, 0x114)
        SHR_V2_STEP(av1, av2, 0x118) SHR_V2_STEP(bv1, bv2, 0x118)
        u32 Va, V2a, Vb, V2b;
        {
            u32 p1 = readlane32(av1, 15), p2 = readlane32(av2, 15);
            u32 q1 = readlane32(av1, 31), q2 = readlane32(av2, 31);
            u32 s1 = readlane32(av1, 47), s2 = readlane32(av2, 47);
            u32 w1 = readlane32(av1, 63), w2 = readlane32(av2, 63);
            u32 mn = p1 < q1 ? p1 : q1; p1 = p1 > q1 ? p1 : q1;
            p2 = p2 > q2 ? p2 : q2; p2 = p2 > mn ? p2 : mn;
            mn = s1 < w1 ? s1 : w1; s1 = s1 > w1 ? s1 : w1;
            s2 = s2 > w2 ? s2 : w2; s2 = s2 > mn ? s2 : mn;
            mn = p1 < s1 ? p1 : s1; p1 = p1 > s1 ? p1 : s1;
            p2 = p2 > s2 ? p2 : s2; p2 = p2 > mn ? p2 : mn;
            Va = p1; V2a = p2;
        }
        {
            u32 p1 = readlane32(bv1, 15), p2 = readlane32(bv2, 15);
            u32 q1 = readlane32(bv1, 31), q2 = readlane32(bv2, 31);
            u32 s1 = readlane32(bv1, 47), s2 = readlane32(bv2, 47);
            u32 w1 = readlane32(bv1, 63), w2 = readlane32(bv2, 63);
            u32 mn = p1 < q1 ? p1 : q1; p1 = p1 > q1 ? p1 : q1;
            p2 = p2 > q2 ? p2 : q2; p2 = p2 > mn ? p2 : mn;
            mn = s1 < w1 ? s1 : w1; s1 = s1 > w1 ? s1 : w1;
            s2 = s2 > w2 ? s2 : w2; s2 = s2 > mn ? s2 : mn;
            mn = p1 < s1 ? p1 : s1; p1 = p1 > s1 ? p1 : s1;
            p2 = p2 > s2 ? p2 : s2; p2 = p2 > mn ? p2 : mn;
            Vb = p1; V2b = p2;
        }
        if (Va == 0) oa = 0ull;
        else if (V2a == Va) oa = UNK;                    // tie -> exact rescan
        else {
            u64 ball = __ballot(sva == Va);
            int wl = (int)__ffsll(ball) - 1;
            u32 lbl = readlane32(sla, wl);
            oa = ((u64)Va << 32) | lbl;
        }
        if (!hb) { ob = 0ull; return; }
        if (Vb == 0) ob = 0ull;
        else if (V2b == Vb) ob = UNK;
        else {
            u64 ball = __ballot(svb == Vb);
            int wl = (int)__ffsll(ball) - 1;
            u32 lbl = readlane32(slb, wl);
            ob = ((u64)Vb << 32) | lbl;
        }
    };

    // commit helper (called by lane 0 only); cub value already stored by caller
    auto try_commit = [&](int c, u64 cbv) {
        u64 sb = colbest[c];
        if (sb && cbv && !((cbv >> 16) & 1ull) &&
            (u32)(cbv & 1023ull) == (u32)(sb & 1023ull)) {
            int L = (int)(sb & 1023ull);
            seenc[c] = 1; lockedl[L] = 1; rkey[L] = 0ull;
            dest_s[L] = (u16)c; perm_s[c] = (u16)L;
            atomicOr(&seenw[c >> 5], 1u << (c & 31));
            atomicOr(&lockedw[L >> 5], 1u << (L & 31));
            atomicAdd(&ncommit, 1);
        }
    };

    if (!rkey_ws) {   // in-kernel init fallback
        for (int L = 2 * wid; L < NBOX; L += 32) {
            u64 r1a, r2a, r1b, r2b;
            scan_row2(L, L + 1, true, r1a, r2a, r1b, r2b);
            store_rkey(L, r1a, r2a);
            store_rkey(L + 1, r1b, r2b);
        }
        for (int c = 2 * wid; c < NBOX; c += 32) {
            u64 oa, ob;
            scan_col2(c, c + 1, true, oa, ob);
            if (oa == UNK) oa = scan_col_exact(c);
            if (ob == UNK) ob = scan_col_exact(c + 1);
            if (lane == 0) { cub[c] = oa; cub[c + 1] = ob; }
        }
        __syncthreads();
    }

    for (int round = 0; round < 2048; ++round) {
        // ---- C: suitor push (+ counter reset) ----
        {
            u64 k = rkey[t];
            if (k) atomicMax((unsigned long long*)&colbest[k & 1023ull],
                             ((k >> 10) << 20) | ((u64)pos_s[t] << 10) | (u64)(unsigned)t);
            if (t == 0) ncommit = 0;
        }
        __syncthreads();

        // ---- DEF: fast check -> paired ballot scans -> immediate commit apply ----
        {
            bool need = false;
            u64 sb = colbest[t];
            if (sb) {
                u32 sval = (u32)(sb >> 20);
                u32 slab = (u32)(sb & 1023ull);
                u64 cb = cub[t];
                u32 cval = (u32)(cb >> 32);
                u32 clab = (u32)(cb & 1023ull);
                bool ctie = (cb >> 16) & 1ull;
                if (lockedl[clab] || ctie || (sval == cval && slab != clab)) {
                    need = true;
                } else if (slab == clab) {        // dominant pair: commit now
                    int c = t, L = (int)slab;
                    seenc[c] = 1; lockedl[L] = 1; rkey[L] = 0ull;
                    dest_s[L] = (u16)c; perm_s[c] = (u16)L;
                    atomicOr(&seenw[c >> 5], 1u << (c & 31));
                    atomicOr(&lockedw[L >> 5], 1u << (L & 31));
                    atomicAdd(&ncommit, 1);
                }
            }
            u64 bal = __ballot(need);
            while (bal) {
                int l0 = (int)__ffsll(bal) - 1; bal &= bal - 1;
                int l1 = l0; bool hb = false;
                if (bal) { l1 = (int)__ffsll(bal) - 1; bal &= bal - 1; hb = true; }
                int c0 = (wid << 6) | l0, c1 = (wid << 6) | l1;
                u64 o0, o1;
                scan_col2(c0, c1, hb, o0, o1);
                if (o0 == UNK) o0 = scan_col_exact(c0);
                if (hb && o1 == UNK) o1 = scan_col_exact(c1);
                if (lane == 0) {
                    cub[c0] = o0; try_commit(c0, o0);
                    if (hb) { cub[c1] = o1; try_commit(c1, o1); }
                }
            }
        }
        __syncthreads();

        // ---- H: rebuild masks, promote rows (+paired scans), chase, clear suitors ----
        const int nc = ncommit;
        {
            u32 ms = 0, ml = 0;
            #pragma unroll
            for (int m = 0; m < 4; ++m) {
                u32 ws_ = seenw[(lane >> 3) + (m << 3)];
                u32 wl  = lockedw[(lane >> 3) + (m << 3)];
                u32 sh  = (lane & 7) << 2;
                ms |= ((ws_ >> sh) & 0xFu) << (m << 2);
                ml |= ((wl  >> sh) & 0xFu) << (m << 2);
            }
            myseen = ms; mylocked = ml;
        }
        {
            bool needrow = false;
            u64 k = rkey[t];
            if (k && seenc[k & 1023ull]) {
                u64 k2 = rkey2[t];
                if (k2 != UNK) {
                    rkey[t] = k2;                 // exact promotion (or dead if 0)
                    rkey2[t] = UNK;
                    if (k2 && seenc[k2 & 1023ull]) needrow = true;
                } else {
                    needrow = true;
                }
            }
            u64 bal = __ballot(needrow);
            while (bal) {
                int l0 = (int)__ffsll(bal) - 1; bal &= bal - 1;
                int l1 = l0; bool hb = false;
                if (bal) { l1 = (int)__ffsll(bal) - 1; bal &= bal - 1; hb = true; }
                int r0 = (wid << 6) | l0, r1_ = (wid << 6) | l1;
                u64 r1a, r2a, r1b, r2b;
                scan_row2(r0, r1_, hb, r1a, r2a, r1b, r2b);
                store_rkey(r0, r1a, r2a);
                if (hb) store_rkey(r1_, r1b, r2b);
            }
        }
        colbest[t] = 0ull;
        if (!seenc[t]) {
            int l = (int)perm_s[t];               // resume from last endpoint
            while (lockedl[l]) l = (int)dest_s[l];
            pos_s[l] = (u16)t;
            perm_s[t] = (u16)l;
        }
        __syncthreads();

        if (nc == 0) break;                       // no live positive keys -> perm final
    }

    // ---- loss = mean |labels[perm] - predictions| ----
    {
        float4 lb = lab4s[perm_s[t]];
        float4 pb = pred4s[t];
        float sum = fabsf(lb.x - pb.x) + fabsf(lb.y - pb.y) +
                    fabsf(lb.z - pb.z) + fabsf(lb.w - pb.w);
        for (int off = 32; off > 0; off >>= 1) sum += __shfl_xor(sum, off, 64);
        if (lane == 0) fpart[wid] = sum;
        __syncthreads();
        if (t == 0) {
            float s = 0.0f;
            for (int w = 0; w < 16; ++w) s += fpart[w];
            out[0] = s * (1.0f / 4096.0f);
        }
    }
}

extern "C" void kernel_launch(void* const* d_in, const int* in_sizes, int n_in,
                              void* d_out, int out_size, void* d_ws, size_t ws_size,
                              hipStream_t stream) {
    const float* preds  = (const float*)d_in[0];   // predictions [1024,4]
    const float* labels = (const float*)d_in[1];   // labels      [1024,4]
    float* out = (float*)d_out;

    const size_t jm_b   = (size_t)NBOX * NBOX * sizeof(float);   // 4 MB
    const size_t keys_b = 3 * NBOX * sizeof(u64);                // 24 KB

    float *JM = nullptr, *JMT = nullptr;
    u64 *rk = nullptr, *rk2 = nullptr, *cb = nullptr;
    char* w = (char*)d_ws;

    if (d_ws && ws_size >= 2 * jm_b + keys_b) {
        JM  = (float*)w;
        JMT = (float*)(w + jm_b);
        rk  = (u64*)(w + 2 * jm_b); rk2 = rk + NBOX; cb = rk2 + NBOX;
    } else if (d_ws && ws_size >= jm_b + keys_b) {
        JM  = (float*)w;
        rk  = (u64*)(w + jm_b); rk2 = rk + NBOX; cb = rk2 + NBOX;
    } else if (d_ws && ws_size >= keys_b) {
        rk  = (u64*)w; rk2 = rk + NBOX; cb = rk2 + NBOX;
    }

    if (rk) {
        jm_init<<<NBOX, 64, 0, stream>>>(labels, preds, JM, rk, rk2);
        init_colmax<<<NBOX, 64, 0, stream>>>(labels, preds, JMT, cb);
    }
    rounds_kernel<<<1, 1024, 0, stream>>>(preds, labels, JM, JMT, rk, rk2, cb, out);
}